// Round 1
// baseline (589.310 us; speedup 1.0000x reference)
//
#include <hip/hip_runtime.h>
#include <stdint.h>

#define T_DIM 2048
#define B_DIM 2
#define D_DIM 1024
#define H_DIM 16
#define DH    64
#define G_DIM 32          // B*H
#define N_ROWS 4096       // T*B
#define K_DIM 1024

typedef __bf16 bf16x8 __attribute__((ext_vector_type(8)));
typedef float  f32x4  __attribute__((ext_vector_type(4)));
typedef int    i32x4  __attribute__((ext_vector_type(4)));

// ---------- bf16 split helpers (RNE, matches HW bf16 rounding) ----------
static __device__ __forceinline__ unsigned short f32_to_bf16_rne(float f) {
  unsigned u = __float_as_uint(f);
  u += 0x7FFFu + ((u >> 16) & 1u);
  return (unsigned short)(u >> 16);
}
static __device__ __forceinline__ float bf16_to_f32(unsigned short h) {
  return __uint_as_float(((unsigned)h) << 16);
}

static __device__ __forceinline__ void split4_store(const float* __restrict__ src,
                                                    unsigned short* __restrict__ hi,
                                                    unsigned short* __restrict__ lo,
                                                    size_t i4) {
  float4 x = *reinterpret_cast<const float4*>(src + i4);
  ushort4 h, l;
  { float f = x.x; h.x = f32_to_bf16_rne(f); l.x = f32_to_bf16_rne(f - bf16_to_f32(h.x)); }
  { float f = x.y; h.y = f32_to_bf16_rne(f); l.y = f32_to_bf16_rne(f - bf16_to_f32(h.y)); }
  { float f = x.z; h.z = f32_to_bf16_rne(f); l.z = f32_to_bf16_rne(f - bf16_to_f32(h.z)); }
  { float f = x.w; h.w = f32_to_bf16_rne(f); l.w = f32_to_bf16_rne(f - bf16_to_f32(h.w)); }
  *reinterpret_cast<ushort4*>(hi + i4) = h;
  *reinterpret_cast<ushort4*>(lo + i4) = l;
}

__global__ __launch_bounds__(256) void split_x_kernel(const float* __restrict__ src,
                                                      unsigned short* __restrict__ hi,
                                                      unsigned short* __restrict__ lo) {
  size_t i4 = ((size_t)blockIdx.x * 256 + threadIdx.x) * 4;
  split4_store(src, hi, lo, i4);
}

__global__ __launch_bounds__(256) void split_w_kernel(const float* __restrict__ w0,
                                                      const float* __restrict__ w1,
                                                      const float* __restrict__ w2,
                                                      const float* __restrict__ w3,
                                                      unsigned short* __restrict__ hi,
                                                      unsigned short* __restrict__ lo) {
  const int z = blockIdx.z;
  const float* src = (z == 0) ? w0 : (z == 1) ? w1 : (z == 2) ? w2 : w3;
  size_t base = (size_t)z * (D_DIM * D_DIM);
  size_t i4 = ((size_t)blockIdx.x * 256 + threadIdx.x) * 4;
  split4_store(src, hi + base, lo + base, i4);
}

// ---------- bf16x3 GEMM: C[M,N] = (A[M,K] @ W[N,K]^T + bias) * alpha ----------
// Direct-from-global MFMA fragments. A-frag row=l&15, k=(l>>4)*8+j ; B-frag col=l&15.
// wave tile 64x64 (rt=4, jt=4), block = 4 waves stacked on rows -> 256x64 tile.
static __device__ __forceinline__ bf16x8 ldfrag(const unsigned short* __restrict__ p,
                                                int row, int k0, int lane) {
  return *reinterpret_cast<const bf16x8*>(p + (size_t)(row + (lane & 15)) * K_DIM + k0 +
                                          ((lane >> 4) << 3));
}

__global__ __launch_bounds__(256) void gemm_bf16x3_kernel(
    const unsigned short* __restrict__ Ahi, const unsigned short* __restrict__ Alo,
    const unsigned short* __restrict__ Whi, const unsigned short* __restrict__ Wlo,
    const float* __restrict__ bias, float* __restrict__ C,
    unsigned* __restrict__ amax_bits, float alpha) {
  const int lane = threadIdx.x & 63, wave = threadIdx.x >> 6;
  const int row0 = blockIdx.x * 256 + wave * 64;
  const int col0 = blockIdx.y * 64;
  f32x4 acc[4][4];
#pragma unroll
  for (int i = 0; i < 4; ++i)
#pragma unroll
    for (int j = 0; j < 4; ++j) acc[i][j] = f32x4{0.f, 0.f, 0.f, 0.f};

  for (int k0 = 0; k0 < K_DIM; k0 += 32) {
    bf16x8 ah[4], al[4];
#pragma unroll
    for (int rt = 0; rt < 4; ++rt) {
      ah[rt] = ldfrag(Ahi, row0 + rt * 16, k0, lane);
      al[rt] = ldfrag(Alo, row0 + rt * 16, k0, lane);
    }
#pragma unroll
    for (int jt = 0; jt < 4; ++jt) {
      bf16x8 bh = ldfrag(Whi, col0 + jt * 16, k0, lane);
      bf16x8 bl = ldfrag(Wlo, col0 + jt * 16, k0, lane);
#pragma unroll
      for (int rt = 0; rt < 4; ++rt) {
        acc[rt][jt] = __builtin_amdgcn_mfma_f32_16x16x32_bf16(ah[rt], bh, acc[rt][jt], 0, 0, 0);
        acc[rt][jt] = __builtin_amdgcn_mfma_f32_16x16x32_bf16(ah[rt], bl, acc[rt][jt], 0, 0, 0);
        acc[rt][jt] = __builtin_amdgcn_mfma_f32_16x16x32_bf16(al[rt], bh, acc[rt][jt], 0, 0, 0);
      }
    }
  }
  const int rb = (lane >> 4) * 4, cb = lane & 15;
  float bj[4];
#pragma unroll
  for (int jt = 0; jt < 4; ++jt) bj[jt] = bias[col0 + jt * 16 + cb];
  float am = 0.f;
#pragma unroll
  for (int rt = 0; rt < 4; ++rt)
#pragma unroll
    for (int jt = 0; jt < 4; ++jt)
#pragma unroll
      for (int r = 0; r < 4; ++r) {
        float v = (acc[rt][jt][r] + bj[jt]) * alpha;
        C[(size_t)(row0 + rt * 16 + rb + r) * D_DIM + col0 + jt * 16 + cb] = v;
        am = fmaxf(am, fabsf(v));
      }
#pragma unroll
  for (int s = 32; s; s >>= 1) am = fmaxf(am, __shfl_xor(am, s));
  __shared__ unsigned sam;
  if (threadIdx.x == 0) sam = 0u;
  __syncthreads();
  if (lane == 0) atomicMax(&sam, __float_as_uint(am));
  __syncthreads();
  if (threadIdx.x == 0) atomicMax(amax_bits, sam);
}

// ---------- quantize q,k into [g][t][dh] int8 (also inits minZ scalar) ----------
__global__ __launch_bounds__(256) void quant_qk_kernel(const float* __restrict__ q32,
                                                       const float* __restrict__ k32,
                                                       signed char* __restrict__ qi8,
                                                       signed char* __restrict__ ki8,
                                                       unsigned* __restrict__ scal) {
  if (blockIdx.x == 0 && blockIdx.y == 0 && threadIdx.x == 0) scal[4] = 0x7F800000u;  // minZ=+inf
  const int which = blockIdx.y;
  const float* src = which ? k32 : q32;
  signed char* dst = which ? ki8 : qi8;
  const float s = __uint_as_float(scal[which]) / 127.0f + 1e-8f;
  size_t i4 = ((size_t)blockIdx.x * 256 + threadIdx.x) * 4;
  float4 x = *reinterpret_cast<const float4*>(src + i4);
  int d = (int)(i4 & (D_DIM - 1));
  int row = (int)(i4 >> 10);
  int t = row >> 1, b = row & 1;
  int h = d >> 6, dh = d & 63;
  char4 c;
  { float q = rintf(x.x / s); q = fminf(127.f, fmaxf(-127.f, q)); c.x = (signed char)q; }
  { float q = rintf(x.y / s); q = fminf(127.f, fmaxf(-127.f, q)); c.y = (signed char)q; }
  { float q = rintf(x.z / s); q = fminf(127.f, fmaxf(-127.f, q)); c.z = (signed char)q; }
  { float q = rintf(x.w / s); q = fminf(127.f, fmaxf(-127.f, q)); c.w = (signed char)q; }
  *reinterpret_cast<char4*>(dst + (((size_t)(b * H_DIM + h) * T_DIM + t) * DH + dh)) = c;
}

// ---------- quantize v and transpose to [g][dh][t] int8 ----------
__global__ __launch_bounds__(256) void quant_v_kernel(const float* __restrict__ v32,
                                                      signed char* __restrict__ viT8,
                                                      const unsigned* __restrict__ scal) {
  const float s = __uint_as_float(scal[2]) / 127.0f + 1e-8f;
  const int g = blockIdx.y, t0 = blockIdx.x * 64;
  const int b = g >> 4, h = g & 15;
  __shared__ signed char tile[64][68];
  const int tid = threadIdx.x;
#pragma unroll
  for (int rep = 0; rep < 4; ++rep) {
    int tl = tid >> 2;
    int f4 = (tid & 3) + rep * 4;
    const float* p = v32 + ((size_t)(t0 + tl) * B_DIM + b) * D_DIM + h * 64 + f4 * 4;
    float4 x = *reinterpret_cast<const float4*>(p);
    char4 c;
    { float q = rintf(x.x / s); q = fminf(127.f, fmaxf(-127.f, q)); c.x = (signed char)q; }
    { float q = rintf(x.y / s); q = fminf(127.f, fmaxf(-127.f, q)); c.y = (signed char)q; }
    { float q = rintf(x.z / s); q = fminf(127.f, fmaxf(-127.f, q)); c.z = (signed char)q; }
    { float q = rintf(x.w / s); q = fminf(127.f, fmaxf(-127.f, q)); c.w = (signed char)q; }
    *reinterpret_cast<char4*>(&tile[tl][f4 * 4]) = c;
  }
  __syncthreads();
  const int dh = tid >> 2, tq = tid & 3;
  signed char outb[16];
#pragma unroll
  for (int j = 0; j < 16; ++j) outb[j] = tile[tq * 16 + j][dh];
  i32x4 vv;
  __builtin_memcpy(&vv, outb, 16);
  *reinterpret_cast<i32x4*>(viT8 + ((size_t)g * DH + dh) * T_DIM + t0 + tq * 16) = vv;
}

// ---------- pass1: global max|idot| over all scores ----------
__global__ __launch_bounds__(256) void attn_smax_kernel(const signed char* __restrict__ qi8,
                                                        const signed char* __restrict__ ki8,
                                                        unsigned* __restrict__ scal) {
  const int lane = threadIdx.x & 63, wave = threadIdx.x >> 6;
  const int g = blockIdx.y;
  const int qbase = blockIdx.x * 64 + wave * 16;
  const int lo = lane & 15, hi4 = lane >> 4;
  const signed char* qg = qi8 + (size_t)g * T_DIM * DH;
  const signed char* kg = ki8 + (size_t)g * T_DIM * DH;
  i32x4 afr = *reinterpret_cast<const i32x4*>(qg + (size_t)(qbase + lo) * DH + hi4 * 16);
  const i32x4 zero = {0, 0, 0, 0};
  int m = 0;
  for (int kc = 0; kc < T_DIM; kc += 16) {
    i32x4 bfr = *reinterpret_cast<const i32x4*>(kg + (size_t)(kc + lo) * DH + hi4 * 16);
    i32x4 sc = __builtin_amdgcn_mfma_i32_16x16x64_i8(afr, bfr, zero, 0, 0, 0);
#pragma unroll
    for (int r = 0; r < 4; ++r) { int a = sc[r] < 0 ? -sc[r] : sc[r]; m = a > m ? a : m; }
  }
#pragma unroll
  for (int s = 32; s; s >>= 1) { int o = __shfl_xor(m, s); m = o > m ? o : m; }
  __shared__ int sm;
  if (threadIdx.x == 0) sm = 0;
  __syncthreads();
  if (lane == 0) atomicMax(&sm, m);
  __syncthreads();
  if (threadIdx.x == 0) atomicMax((int*)&scal[3], sm);
}

// ---------- pass2: per-row lmax & Z of quantized-score softmax; global min Z ----------
__global__ __launch_bounds__(256) void attn_stats_kernel(const signed char* __restrict__ qi8,
                                                         const signed char* __restrict__ ki8,
                                                         unsigned* __restrict__ scal,
                                                         float* __restrict__ rowZ,
                                                         float* __restrict__ rowL) {
  const float sq = __uint_as_float(scal[0]) / 127.0f + 1e-8f;
  const float sk = __uint_as_float(scal[1]) / 127.0f + 1e-8f;
  const float sqsk = sq * sk;
  const float smax = sqsk * (float)(int)scal[3];
  const float s_s = smax / 127.0f + 1e-8f;
  const float ratio = sqsk / s_s;
  const float c127 = -127.0f * s_s;
  const int lane = threadIdx.x & 63, wave = threadIdx.x >> 6;
  const int g = blockIdx.y;
  const int qbase = blockIdx.x * 64 + wave * 16;
  const int lo = lane & 15, hi4 = lane >> 4;
  const signed char* qg = qi8 + (size_t)g * T_DIM * DH;
  const signed char* kg = ki8 + (size_t)g * T_DIM * DH;
  i32x4 afr = *reinterpret_cast<const i32x4*>(qg + (size_t)(qbase + lo) * DH + hi4 * 16);
  const i32x4 zero = {0, 0, 0, 0};
  float lmax[4] = {-1e30f, -1e30f, -1e30f, -1e30f};
  float zp[4] = {0.f, 0.f, 0.f, 0.f};
  for (int kc = 0; kc < T_DIM; kc += 16) {
    i32x4 bfr = *reinterpret_cast<const i32x4*>(kg + (size_t)(kc + lo) * DH + hi4 * 16);
    i32x4 sc = __builtin_amdgcn_mfma_i32_16x16x64_i8(afr, bfr, zero, 0, 0, 0);
#pragma unroll
    for (int r = 0; r < 4; ++r) {
      float lf = rintf((float)sc[r] * ratio);
      lmax[r] = fmaxf(lmax[r], lf);
      zp[r] += __expf(fmaf(lf, s_s, c127));  // exp((l-127)*s_s): safe, rescaled below
    }
  }
#pragma unroll
  for (int s = 1; s < 16; s <<= 1) {
#pragma unroll
    for (int r = 0; r < 4; ++r) {
      lmax[r] = fmaxf(lmax[r], __shfl_xor(lmax[r], s));
      zp[r] += __shfl_xor(zp[r], s);
    }
  }
  float zloc = 1e30f;
  if ((lane & 15) == 0) {
#pragma unroll
    for (int r = 0; r < 4; ++r) {
      int row = qbase + hi4 * 4 + r;
      float Z = zp[r] * __expf((127.0f - lmax[r]) * s_s);  // true softmax denom, <=2048
      rowZ[(size_t)g * T_DIM + row] = Z;
      rowL[(size_t)g * T_DIM + row] = lmax[r];
      zloc = fminf(zloc, Z);
    }
  }
  __shared__ unsigned szm;
  if (threadIdx.x == 0) szm = 0x7F800000u;
  __syncthreads();
  if ((lane & 15) == 0) atomicMin(&szm, __float_as_uint(zloc));
  __syncthreads();
  if (threadIdx.x == 0) atomicMin(&scal[4], szm);
}

// ---------- pass3: recompute scores -> quantized probs -> PV (i8 MFMA), attn absmax ----------
__global__ __launch_bounds__(256) void attn_pv_kernel(const signed char* __restrict__ qi8,
                                                      const signed char* __restrict__ ki8,
                                                      const signed char* __restrict__ viT8,
                                                      const float* __restrict__ rowZ,
                                                      const float* __restrict__ rowL,
                                                      unsigned* __restrict__ scal,
                                                      int* __restrict__ attn_out) {
  const float sq = __uint_as_float(scal[0]) / 127.0f + 1e-8f;
  const float sk = __uint_as_float(scal[1]) / 127.0f + 1e-8f;
  const float sqsk = sq * sk;
  const float smax = sqsk * (float)(int)scal[3];
  const float s_s = smax / 127.0f + 1e-8f;
  const float ratio = sqsk / s_s;
  const float maxp = 1.0f / __uint_as_float(scal[4]);
  const float s_p = maxp / 127.0f + 1e-8f;
  const float inv_sp = 1.0f / s_p;
  const int lane = threadIdx.x & 63, wave = threadIdx.x >> 6;
  const int g = blockIdx.y;
  const int qbase = blockIdx.x * 64 + wave * 16;
  const int lo = lane & 15, hi4 = lane >> 4;
  const signed char* qg = qi8 + (size_t)g * T_DIM * DH;
  const signed char* kg = ki8 + (size_t)g * T_DIM * DH;
  i32x4 afr = *reinterpret_cast<const i32x4*>(qg + (size_t)(qbase + lo) * DH + hi4 * 16);
  float rcpz[4], lmaxr[4];
#pragma unroll
  for (int r = 0; r < 4; ++r) {
    int row = qbase + hi4 * 4 + r;
    rcpz[r] = 1.0f / rowZ[(size_t)g * T_DIM + row];
    lmaxr[r] = rowL[(size_t)g * T_DIM + row];
  }
  __shared__ __align__(16) signed char pbuf[4][16][64];
  const i32x4 zero = {0, 0, 0, 0};
  i32x4 accv[4];
#pragma unroll
  for (int dt = 0; dt < 4; ++dt) accv[dt] = zero;

  for (int kc = 0; kc < T_DIM; kc += 64) {
#pragma unroll
    for (int t4 = 0; t4 < 4; ++t4) {
      i32x4 bfr =
          *reinterpret_cast<const i32x4*>(kg + (size_t)(kc + t4 * 16 + lo) * DH + hi4 * 16);
      i32x4 sc = __builtin_amdgcn_mfma_i32_16x16x64_i8(afr, bfr, zero, 0, 0, 0);
#pragma unroll
      for (int r = 0; r < 4; ++r) {
        float lf = rintf((float)sc[r] * ratio);
        float p = __expf((lf - lmaxr[r]) * s_s) * rcpz[r];
        float pl = fminf(rintf(p * inv_sp), 127.0f);
        pbuf[wave][hi4 * 4 + r][t4 * 16 + lo] = (signed char)pl;
      }
    }
    asm volatile("s_waitcnt lgkmcnt(0)" ::: "memory");
    i32x4 pfr = *reinterpret_cast<const i32x4*>(&pbuf[wave][lo][hi4 * 16]);
#pragma unroll
    for (int dt = 0; dt < 4; ++dt) {
      const signed char* vp = viT8 + ((size_t)g * DH + dt * 16 + lo) * T_DIM + kc + hi4 * 16;
      i32x4 vfr = *reinterpret_cast<const i32x4*>(vp);
      accv[dt] = __builtin_amdgcn_mfma_i32_16x16x64_i8(pfr, vfr, accv[dt], 0, 0, 0);
    }
  }
  int am = 0;
#pragma unroll
  for (int dt = 0; dt < 4; ++dt)
#pragma unroll
    for (int r = 0; r < 4; ++r) {
      int v = accv[dt][r];
      attn_out[((size_t)g * T_DIM + qbase + hi4 * 4 + r) * DH + dt * 16 + lo] = v;
      int a = v < 0 ? -v : v;
      am = a > am ? a : am;
    }
#pragma unroll
  for (int s = 32; s; s >>= 1) { int o = __shfl_xor(am, s); am = o > am ? o : am; }
  __shared__ int sm;
  if (threadIdx.x == 0) sm = 0;
  __syncthreads();
  if (lane == 0) atomicMax(&sm, am);
  __syncthreads();
  if (threadIdx.x == 0) atomicMax((int*)&scal[5], sm);
}

// ---------- pass4: fake-quant attn, reorder [g][t][dh] -> (t,b,d), split to bf16 hi/lo ----------
__global__ __launch_bounds__(256) void quant_attn_kernel(const int* __restrict__ attn_i32,
                                                         unsigned short* __restrict__ aq_hi,
                                                         unsigned short* __restrict__ aq_lo,
                                                         const unsigned* __restrict__ scal) {
  const float sv = __uint_as_float(scal[2]) / 127.0f + 1e-8f;
  const float maxp = 1.0f / __uint_as_float(scal[4]);
  const float s_p = maxp / 127.0f + 1e-8f;
  const float spsv = s_p * sv;
  const float amax = spsv * (float)(int)scal[5];
  const float s_a = amax / 127.0f + 1e-8f;
  size_t i4 = ((size_t)blockIdx.x * 256 + threadIdx.x) * 4;
  i32x4 iv = *reinterpret_cast<const i32x4*>(attn_i32 + i4);
  int dh0 = (int)(i4 & 63);
  int t = (int)((i4 >> 6) & (T_DIM - 1));
  int g = (int)(i4 >> 17);
  int b = g >> 4, h = g & 15;
  ushort4 hh, ll;
  { float a = (float)iv[0] * spsv; float lf = fminf(127.f, fmaxf(-127.f, rintf(a / s_a)));
    float qv = lf * s_a; hh.x = f32_to_bf16_rne(qv); ll.x = f32_to_bf16_rne(qv - bf16_to_f32(hh.x)); }
  { float a = (float)iv[1] * spsv; float lf = fminf(127.f, fmaxf(-127.f, rintf(a / s_a)));
    float qv = lf * s_a; hh.y = f32_to_bf16_rne(qv); ll.y = f32_to_bf16_rne(qv - bf16_to_f32(hh.y)); }
  { float a = (float)iv[2] * spsv; float lf = fminf(127.f, fmaxf(-127.f, rintf(a / s_a)));
    float qv = lf * s_a; hh.z = f32_to_bf16_rne(qv); ll.z = f32_to_bf16_rne(qv - bf16_to_f32(hh.z)); }
  { float a = (float)iv[3] * spsv; float lf = fminf(127.f, fmaxf(-127.f, rintf(a / s_a)));
    float qv = lf * s_a; hh.w = f32_to_bf16_rne(qv); ll.w = f32_to_bf16_rne(qv - bf16_to_f32(hh.w)); }
  size_t o = (size_t)(t * B_DIM + b) * D_DIM + h * 64 + dh0;
  *reinterpret_cast<ushort4*>(aq_hi + o) = hh;
  *reinterpret_cast<ushort4*>(aq_lo + o) = ll;
}

// ---------------- launch ----------------
extern "C" void kernel_launch(void* const* d_in, const int* in_sizes, int n_in,
                              void* d_out, int out_size, void* d_ws, size_t ws_size,
                              hipStream_t stream) {
  (void)in_sizes; (void)n_in; (void)out_size;
  const float* x  = (const float*)d_in[0];
  const float* wq = (const float*)d_in[1];
  const float* bq = (const float*)d_in[2];
  const float* wk = (const float*)d_in[3];
  const float* bk = (const float*)d_in[4];
  const float* wv = (const float*)d_in[5];
  const float* bv = (const float*)d_in[6];
  const float* wo = (const float*)d_in[7];
  const float* bo = (const float*)d_in[8];
  float* out = (float*)d_out;
  char* ws = (char*)d_ws;

  constexpr size_t SZ_ROW   = (size_t)G_DIM * T_DIM * 4;        // 256 KiB
  constexpr size_t SZ_XSPL  = (size_t)N_ROWS * D_DIM * 2;       // 8 MiB
  constexpr size_t SZ_WSPL  = (size_t)4 * D_DIM * D_DIM * 2;    // 8 MiB
  constexpr size_t SZ_F32   = (size_t)N_ROWS * D_DIM * 4;       // 16 MiB
  constexpr size_t SZ_I8    = (size_t)G_DIM * T_DIM * DH;       // 4 MiB
  constexpr size_t OFF_ROWZ = 256;
  constexpr size_t OFF_ROWL = OFF_ROWZ + SZ_ROW;
  constexpr size_t OFF_XHI  = OFF_ROWL + SZ_ROW;
  constexpr size_t OFF_XLO  = OFF_XHI + SZ_XSPL;
  constexpr size_t OFF_WHI  = OFF_XLO + SZ_XSPL;
  constexpr size_t OFF_WLO  = OFF_WHI + SZ_WSPL;
  constexpr size_t OFF_Q32  = OFF_WLO + SZ_WSPL;
  constexpr size_t OFF_K32  = OFF_Q32 + SZ_F32;
  constexpr size_t OFF_V32  = OFF_K32 + SZ_F32;
  constexpr size_t OFF_QI8  = OFF_V32 + SZ_F32;
  constexpr size_t OFF_KI8  = OFF_QI8 + SZ_I8;
  constexpr size_t OFF_VIT8 = OFF_KI8 + SZ_I8;
  constexpr size_t OFF_END  = OFF_VIT8 + SZ_I8;  // ~92.5 MiB
  if (ws_size < OFF_END) return;

  unsigned* scal = (unsigned*)ws;  // [0]amax_q [1]amax_k [2]amax_v [3]score_absint [4]minZ [5]attn_absint [6]dummy
  float* rowZ = (float*)(ws + OFF_ROWZ);
  float* rowL = (float*)(ws + OFF_ROWL);
  unsigned short* x_hi = (unsigned short*)(ws + OFF_XHI);
  unsigned short* x_lo = (unsigned short*)(ws + OFF_XLO);
  unsigned short* w_hi = (unsigned short*)(ws + OFF_WHI);
  unsigned short* w_lo = (unsigned short*)(ws + OFF_WLO);
  float* q32 = (float*)(ws + OFF_Q32);
  float* k32 = (float*)(ws + OFF_K32);
  float* v32 = (float*)(ws + OFF_V32);
  signed char* qi8 = (signed char*)(ws + OFF_QI8);
  signed char* ki8 = (signed char*)(ws + OFF_KI8);
  signed char* viT8 = (signed char*)(ws + OFF_VIT8);
  int* attn_i32 = (int*)(ws + OFF_Q32);             // alias: q32 dead after quant
  unsigned short* aq_hi = x_hi;                     // alias: x splits dead after v-GEMM
  unsigned short* aq_lo = x_lo;

  hipMemsetAsync(ws, 0, 64, stream);
  split_x_kernel<<<4096, 256, 0, stream>>>(x, x_hi, x_lo);
  split_w_kernel<<<dim3(1024, 1, 4), 256, 0, stream>>>(wq, wk, wv, wo, w_hi, w_lo);
  gemm_bf16x3_kernel<<<dim3(16, 16), 256, 0, stream>>>(x_hi, x_lo, w_hi, w_lo, bq, q32,
                                                       scal + 0, 0.125f);
  gemm_bf16x3_kernel<<<dim3(16, 16), 256, 0, stream>>>(x_hi, x_lo, w_hi + 1048576,
                                                       w_lo + 1048576, bk, k32, scal + 1, 1.0f);
  gemm_bf16x3_kernel<<<dim3(16, 16), 256, 0, stream>>>(x_hi, x_lo, w_hi + 2097152,
                                                       w_lo + 2097152, bv, v32, scal + 2, 1.0f);
  quant_qk_kernel<<<dim3(4096, 2), 256, 0, stream>>>(q32, k32, qi8, ki8, scal);
  quant_v_kernel<<<dim3(32, 32), 256, 0, stream>>>(v32, viT8, scal);
  attn_smax_kernel<<<dim3(32, 32), 256, 0, stream>>>(qi8, ki8, scal);
  attn_stats_kernel<<<dim3(32, 32), 256, 0, stream>>>(qi8, ki8, scal, rowZ, rowL);
  attn_pv_kernel<<<dim3(32, 32), 256, 0, stream>>>(qi8, ki8, viT8, rowZ, rowL, scal, attn_i32);
  quant_attn_kernel<<<4096, 256, 0, stream>>>(attn_i32, aq_hi, aq_lo, scal);
  gemm_bf16x3_kernel<<<dim3(16, 16), 256, 0, stream>>>(aq_hi, aq_lo, w_hi + 3145728,
                                                       w_lo + 3145728, bo, out, scal + 6, 1.0f);
}

// Round 2
// 438.097 us; speedup vs baseline: 1.3452x; 1.3452x over previous
//
#include <hip/hip_runtime.h>
#include <stdint.h>

#define T_DIM 2048
#define B_DIM 2
#define D_DIM 1024
#define H_DIM 16
#define DH    64
#define G_DIM 32          // B*H
#define N_ROWS 4096       // T*B
#define K_DIM 1024

typedef __bf16 bf16x8 __attribute__((ext_vector_type(8)));
typedef float  f32x4  __attribute__((ext_vector_type(4)));
typedef int    i32x4  __attribute__((ext_vector_type(4)));

typedef const __attribute__((address_space(1))) unsigned int* gas_u32;
typedef __attribute__((address_space(3))) unsigned int* las_u32;

static __device__ __forceinline__ void gload16(const void* gsrc, void* ldst) {
  __builtin_amdgcn_global_load_lds((gas_u32)gsrc, (las_u32)ldst, 16, 0, 0);
}

// ---------- bf16 split helpers (RNE, matches HW bf16 rounding) ----------
static __device__ __forceinline__ unsigned short f32_to_bf16_rne(float f) {
  unsigned u = __float_as_uint(f);
  u += 0x7FFFu + ((u >> 16) & 1u);
  return (unsigned short)(u >> 16);
}
static __device__ __forceinline__ float bf16_to_f32(unsigned short h) {
  return __uint_as_float(((unsigned)h) << 16);
}

static __device__ __forceinline__ void split4_store(const float* __restrict__ src,
                                                    unsigned short* __restrict__ hi,
                                                    unsigned short* __restrict__ lo,
                                                    size_t i4) {
  float4 x = *reinterpret_cast<const float4*>(src + i4);
  ushort4 h, l;
  { float f = x.x; h.x = f32_to_bf16_rne(f); l.x = f32_to_bf16_rne(f - bf16_to_f32(h.x)); }
  { float f = x.y; h.y = f32_to_bf16_rne(f); l.y = f32_to_bf16_rne(f - bf16_to_f32(h.y)); }
  { float f = x.z; h.z = f32_to_bf16_rne(f); l.z = f32_to_bf16_rne(f - bf16_to_f32(h.z)); }
  { float f = x.w; h.w = f32_to_bf16_rne(f); l.w = f32_to_bf16_rne(f - bf16_to_f32(h.w)); }
  *reinterpret_cast<ushort4*>(hi + i4) = h;
  *reinterpret_cast<ushort4*>(lo + i4) = l;
}

__global__ __launch_bounds__(256) void split_x_kernel(const float* __restrict__ src,
                                                      unsigned short* __restrict__ hi,
                                                      unsigned short* __restrict__ lo) {
  size_t i4 = ((size_t)blockIdx.x * 256 + threadIdx.x) * 4;
  split4_store(src, hi, lo, i4);
}

__global__ __launch_bounds__(256) void split_w_kernel(const float* __restrict__ w0,
                                                      const float* __restrict__ w1,
                                                      const float* __restrict__ w2,
                                                      const float* __restrict__ w3,
                                                      unsigned short* __restrict__ hi,
                                                      unsigned short* __restrict__ lo) {
  const int z = blockIdx.z;
  const float* src = (z == 0) ? w0 : (z == 1) ? w1 : (z == 2) ? w2 : w3;
  size_t base = (size_t)z * (D_DIM * D_DIM);
  size_t i4 = ((size_t)blockIdx.x * 256 + threadIdx.x) * 4;
  split4_store(src, hi + base, lo + base, i4);
}

// ---------- bf16x3 GEMM v2: LDS-staged (m97 structure), fused multi-section N ----------
// C[M=4096,ncols] = (A[4096,1024] @ Wstack[ncols,1024]^T + bias[sec]) * alpha[sec]
// tile 128x64, BK=64, 4 waves (2x2 of 64x32), grid 1-D = 32*(ncols/64), XCD-swizzled.
__global__ __launch_bounds__(256) void gemm_bf16x3_v2(
    const unsigned short* __restrict__ Ahi, const unsigned short* __restrict__ Alo,
    const unsigned short* __restrict__ Whi, const unsigned short* __restrict__ Wlo,
    const float* __restrict__ b0, const float* __restrict__ b1, const float* __restrict__ b2,
    float* __restrict__ C, int ncols, unsigned* __restrict__ scal_base, float alpha0) {
  __shared__ __align__(16) unsigned short sAh[128 * 64];
  __shared__ __align__(16) unsigned short sAl[128 * 64];
  __shared__ __align__(16) unsigned short sWh[64 * 64];
  __shared__ __align__(16) unsigned short sWl[64 * 64];
  __shared__ unsigned sam;
  const int lane = threadIdx.x & 63, wave = threadIdx.x >> 6;
  const int ntn = ncols >> 6;
  const int cpx = gridDim.x >> 3;
  const int bid = blockIdx.x;
  const int swz = (bid & 7) * cpx + (bid >> 3);   // gridDim.x % 8 == 0 always here
  const int tm = swz / ntn, tn = swz - tm * ntn;
  const int rowBase = tm * 128, colBase = tn * 64;
  const int wr = wave >> 1, wc = wave & 1;
  const int lr = lane >> 3, lk = (lane & 7) * 8;
  const int lo = lane & 15, hi4 = lane >> 4;

  f32x4 acc[4][2];
#pragma unroll
  for (int i = 0; i < 4; ++i)
#pragma unroll
    for (int j = 0; j < 2; ++j) acc[i][j] = f32x4{0.f, 0.f, 0.f, 0.f};

  for (int k0 = 0; k0 < K_DIM; k0 += 64) {
    __syncthreads();
#pragma unroll
    for (int i = 0; i < 4; ++i) {
      const int ca = wave * 4 + i;
      const size_t go = (size_t)(rowBase + ca * 8 + lr) * K_DIM + k0 + lk;
      gload16(Ahi + go, &sAh[ca * 512]);
      gload16(Alo + go, &sAl[ca * 512]);
    }
#pragma unroll
    for (int i = 0; i < 2; ++i) {
      const int cw = wave * 2 + i;
      const size_t go = (size_t)(colBase + cw * 8 + lr) * K_DIM + k0 + lk;
      gload16(Whi + go, &sWh[cw * 512]);
      gload16(Wlo + go, &sWl[cw * 512]);
    }
    __syncthreads();
#pragma unroll
    for (int kk = 0; kk < 64; kk += 32) {
      bf16x8 ah[4], al[4], wh[2], wl[2];
#pragma unroll
      for (int rt = 0; rt < 4; ++rt) {
        const int off = (wr * 64 + rt * 16 + lo) * 64 + kk + hi4 * 8;
        ah[rt] = *reinterpret_cast<const bf16x8*>(&sAh[off]);
        al[rt] = *reinterpret_cast<const bf16x8*>(&sAl[off]);
      }
#pragma unroll
      for (int jt = 0; jt < 2; ++jt) {
        const int off = (wc * 32 + jt * 16 + lo) * 64 + kk + hi4 * 8;
        wh[jt] = *reinterpret_cast<const bf16x8*>(&sWh[off]);
        wl[jt] = *reinterpret_cast<const bf16x8*>(&sWl[off]);
      }
#pragma unroll
      for (int jt = 0; jt < 2; ++jt)
#pragma unroll
        for (int rt = 0; rt < 4; ++rt) {
          acc[rt][jt] = __builtin_amdgcn_mfma_f32_16x16x32_bf16(ah[rt], wh[jt], acc[rt][jt], 0, 0, 0);
          acc[rt][jt] = __builtin_amdgcn_mfma_f32_16x16x32_bf16(ah[rt], wl[jt], acc[rt][jt], 0, 0, 0);
          acc[rt][jt] = __builtin_amdgcn_mfma_f32_16x16x32_bf16(al[rt], wh[jt], acc[rt][jt], 0, 0, 0);
        }
    }
  }
  // epilogue: bias + alpha per section, store, absmax
  const int sec = colBase >> 10;
  const float* bp = (sec == 0) ? b0 : ((sec == 1) ? b1 : b2);
  const float alpha = (sec == 0) ? alpha0 : 1.0f;
  const int colL = (colBase & 1023) + wc * 32;
  float bj[2];
#pragma unroll
  for (int jt = 0; jt < 2; ++jt) bj[jt] = bp[colL + jt * 16 + lo];
  float am = 0.f;
#pragma unroll
  for (int rt = 0; rt < 4; ++rt)
#pragma unroll
    for (int jt = 0; jt < 2; ++jt)
#pragma unroll
      for (int r = 0; r < 4; ++r) {
        float v = (acc[rt][jt][r] + bj[jt]) * alpha;
        C[(size_t)(rowBase + wr * 64 + rt * 16 + hi4 * 4 + r) * ncols + colBase + wc * 32 +
          jt * 16 + lo] = v;
        am = fmaxf(am, fabsf(v));
      }
#pragma unroll
  for (int s = 32; s; s >>= 1) am = fmaxf(am, __shfl_xor(am, s));
  if (threadIdx.x == 0) sam = 0u;
  __syncthreads();
  if (lane == 0) atomicMax(&sam, __float_as_uint(am));
  __syncthreads();
  if (threadIdx.x == 0) atomicMax(scal_base + sec, sam);
}

// ---------- quantize q,k into [g][t][dh] int8 (also inits minZ scalar) ----------
__global__ __launch_bounds__(256) void quant_qk_kernel(const float* __restrict__ qkv32,
                                                       signed char* __restrict__ qi8,
                                                       signed char* __restrict__ ki8,
                                                       unsigned* __restrict__ scal) {
  if (blockIdx.x == 0 && blockIdx.y == 0 && threadIdx.x == 0) scal[4] = 0x7F800000u;  // minZ=+inf
  const int which = blockIdx.y;
  signed char* dst = which ? ki8 : qi8;
  const float s = __uint_as_float(scal[which]) / 127.0f + 1e-8f;
  size_t i4 = ((size_t)blockIdx.x * 256 + threadIdx.x) * 4;
  int d = (int)(i4 & (D_DIM - 1));
  int row = (int)(i4 >> 10);
  float4 x = *reinterpret_cast<const float4*>(qkv32 + (size_t)row * 3072 + which * 1024 + d);
  int t = row >> 1, b = row & 1;
  int h = d >> 6, dh = d & 63;
  char4 c;
  { float q = rintf(x.x / s); q = fminf(127.f, fmaxf(-127.f, q)); c.x = (signed char)q; }
  { float q = rintf(x.y / s); q = fminf(127.f, fmaxf(-127.f, q)); c.y = (signed char)q; }
  { float q = rintf(x.z / s); q = fminf(127.f, fmaxf(-127.f, q)); c.z = (signed char)q; }
  { float q = rintf(x.w / s); q = fminf(127.f, fmaxf(-127.f, q)); c.w = (signed char)q; }
  *reinterpret_cast<char4*>(dst + (((size_t)(b * H_DIM + h) * T_DIM + t) * DH + dh)) = c;
}

// ---------- quantize v and transpose to [g][dh][t] int8 ----------
__global__ __launch_bounds__(256) void quant_v_kernel(const float* __restrict__ qkv32,
                                                      signed char* __restrict__ viT8,
                                                      const unsigned* __restrict__ scal) {
  const float s = __uint_as_float(scal[2]) / 127.0f + 1e-8f;
  const int g = blockIdx.y, t0 = blockIdx.x * 64;
  const int b = g >> 4, h = g & 15;
  __shared__ signed char tile[64][68];
  const int tid = threadIdx.x;
#pragma unroll
  for (int rep = 0; rep < 4; ++rep) {
    int tl = tid >> 2;
    int f4 = (tid & 3) + rep * 4;
    const float* p = qkv32 + ((size_t)(t0 + tl) * B_DIM + b) * 3072 + 2048 + h * 64 + f4 * 4;
    float4 x = *reinterpret_cast<const float4*>(p);
    char4 c;
    { float q = rintf(x.x / s); q = fminf(127.f, fmaxf(-127.f, q)); c.x = (signed char)q; }
    { float q = rintf(x.y / s); q = fminf(127.f, fmaxf(-127.f, q)); c.y = (signed char)q; }
    { float q = rintf(x.z / s); q = fminf(127.f, fmaxf(-127.f, q)); c.z = (signed char)q; }
    { float q = rintf(x.w / s); q = fminf(127.f, fmaxf(-127.f, q)); c.w = (signed char)q; }
    *reinterpret_cast<char4*>(&tile[tl][f4 * 4]) = c;
  }
  __syncthreads();
  const int dh = tid >> 2, tq = tid & 3;
  signed char outb[16];
#pragma unroll
  for (int j = 0; j < 16; ++j) outb[j] = tile[tq * 16 + j][dh];
  i32x4 vv;
  __builtin_memcpy(&vv, outb, 16);
  *reinterpret_cast<i32x4*>(viT8 + ((size_t)g * DH + dh) * T_DIM + t0 + tq * 16) = vv;
}

// ---------- in-register 4x4 dword transpose across lanes {lo, lo+16, lo+32, lo+48} ----------
static __device__ __forceinline__ void xpose4(int h, int& p0, int& p1, int& p2, int& p3) {
  const bool b0 = (h & 1), b1 = (h & 2);
  int s0 = __shfl_xor(p0, 16), s1 = __shfl_xor(p1, 16);
  int s2 = __shfl_xor(p2, 16), s3 = __shfl_xor(p3, 16);
  int q0 = b0 ? s1 : p0;
  int q1 = b0 ? p1 : s0;
  int q2 = b0 ? s3 : p2;
  int q3 = b0 ? p3 : s2;
  int u0 = __shfl_xor(q0, 32), u1 = __shfl_xor(q1, 32);
  int u2 = __shfl_xor(q2, 32), u3 = __shfl_xor(q3, 32);
  p0 = b1 ? u2 : q0;
  p1 = b1 ? u3 : q1;
  p2 = b1 ? q2 : u0;
  p3 = b1 ? q3 : u1;
}

// ---------- pass1: global max|idot| over all scores (swapped mfma(K,Q)) ----------
__global__ __launch_bounds__(256) void attn_smax_kernel(const signed char* __restrict__ qi8,
                                                        const signed char* __restrict__ ki8,
                                                        unsigned* __restrict__ scal) {
  const int lane = threadIdx.x & 63, wave = threadIdx.x >> 6;
  const int g = blockIdx.y;
  const int qb = blockIdx.x * 64 + wave * 16;
  const int lo = lane & 15, hi4 = lane >> 4;
  const signed char* qg = qi8 + (size_t)g * T_DIM * DH;
  const signed char* kg = ki8 + (size_t)g * T_DIM * DH;
  const i32x4 qfr = *reinterpret_cast<const i32x4*>(qg + (size_t)(qb + lo) * DH + hi4 * 16);
  const i32x4 zero = {0, 0, 0, 0};
  int mx = -2147483647, mn = 2147483647;
#pragma unroll 4
  for (int kc = 0; kc < T_DIM; kc += 16) {
    i32x4 kfr = *reinterpret_cast<const i32x4*>(kg + (size_t)(kc + lo) * DH + hi4 * 16);
    i32x4 sc = __builtin_amdgcn_mfma_i32_16x16x64_i8(kfr, qfr, zero, 0, 0, 0);
#pragma unroll
    for (int r = 0; r < 4; ++r) { mx = sc[r] > mx ? sc[r] : mx; mn = sc[r] < mn ? sc[r] : mn; }
  }
  int am = mx > -mn ? mx : -mn;
#pragma unroll
  for (int s = 32; s; s >>= 1) { int o = __shfl_xor(am, s); am = o > am ? o : am; }
  __shared__ int sm;
  if (threadIdx.x == 0) sm = 0;
  __syncthreads();
  if (lane == 0) atomicMax(&sm, am);
  __syncthreads();
  if (threadIdx.x == 0) atomicMax((int*)&scal[3], sm);
}

// ---------- pass2: per-row lmax & Z (swapped layout: lane-local rows); global min Z ----------
__global__ __launch_bounds__(256) void attn_stats_kernel(const signed char* __restrict__ qi8,
                                                         const signed char* __restrict__ ki8,
                                                         unsigned* __restrict__ scal,
                                                         float* __restrict__ rowZ,
                                                         float* __restrict__ rowL) {
  const float sq = __uint_as_float(scal[0]) / 127.0f + 1e-8f;
  const float sk = __uint_as_float(scal[1]) / 127.0f + 1e-8f;
  const float sqsk = sq * sk;
  const float smax = sqsk * (float)(int)scal[3];
  const float s_s = smax / 127.0f + 1e-8f;
  const float ratio = sqsk / s_s;
  const float a = s_s * 1.4426950408889634f;   // s_s * log2(e)
  const float c = -127.0f * a;
  const int lane = threadIdx.x & 63, wave = threadIdx.x >> 6;
  const int g = blockIdx.y;
  const int qb = blockIdx.x * 64 + wave * 16;
  const int lo = lane & 15, hi4 = lane >> 4;
  const signed char* qg = qi8 + (size_t)g * T_DIM * DH;
  const signed char* kg = ki8 + (size_t)g * T_DIM * DH;
  const i32x4 qfr = *reinterpret_cast<const i32x4*>(qg + (size_t)(qb + lo) * DH + hi4 * 16);
  const i32x4 zero = {0, 0, 0, 0};
  float mx = -1e30f, zp = 0.f;
#pragma unroll 4
  for (int kc = 0; kc < T_DIM; kc += 16) {
    i32x4 kfr = *reinterpret_cast<const i32x4*>(kg + (size_t)(kc + lo) * DH + hi4 * 16);
    i32x4 sc = __builtin_amdgcn_mfma_i32_16x16x64_i8(kfr, qfr, zero, 0, 0, 0);
#pragma unroll
    for (int r = 0; r < 4; ++r) {
      float lf = rintf((float)sc[r] * ratio);
      mx = fmaxf(mx, lf);
      zp += exp2f(fmaf(lf, a, c));   // exp2((lf-127)*a): bounded by 1, rescaled below
    }
  }
  mx = fmaxf(mx, __shfl_xor(mx, 16)); zp += __shfl_xor(zp, 16);
  mx = fmaxf(mx, __shfl_xor(mx, 32)); zp += __shfl_xor(zp, 32);
  float Z = zp * exp2f((127.0f - mx) * a);   // true softmax denom, <= 2048
  if (hi4 == 0) {
    rowZ[(size_t)g * T_DIM + qb + lo] = Z;
    rowL[(size_t)g * T_DIM + qb + lo] = mx;
  }
  float zm = Z;
#pragma unroll
  for (int s = 32; s; s >>= 1) zm = fminf(zm, __shfl_xor(zm, s));
  __shared__ unsigned szm;
  if (threadIdx.x == 0) szm = 0x7F800000u;
  __syncthreads();
  if (lane == 0) atomicMin(&szm, __float_as_uint(zm));
  __syncthreads();
  if (threadIdx.x == 0) atomicMin(&scal[4], szm);
}

// ---------- pass3: swapped QK -> quantized probs (in-reg) -> shfl-transpose -> PV ----------
__global__ __launch_bounds__(256) void attn_pv_kernel(const signed char* __restrict__ qi8,
                                                      const signed char* __restrict__ ki8,
                                                      const signed char* __restrict__ viT8,
                                                      const float* __restrict__ rowZ,
                                                      const float* __restrict__ rowL,
                                                      unsigned* __restrict__ scal,
                                                      int* __restrict__ attn_out) {
  const float sq = __uint_as_float(scal[0]) / 127.0f + 1e-8f;
  const float sk = __uint_as_float(scal[1]) / 127.0f + 1e-8f;
  const float sqsk = sq * sk;
  const float smax = sqsk * (float)(int)scal[3];
  const float s_s = smax / 127.0f + 1e-8f;
  const float ratio = sqsk / s_s;
  const float a = s_s * 1.4426950408889634f;
  const float maxp = 1.0f / __uint_as_float(scal[4]);
  const float s_p = maxp / 127.0f + 1e-8f;
  const float inv_sp = 1.0f / s_p;
  const int lane = threadIdx.x & 63, wave = threadIdx.x >> 6;
  const int g = blockIdx.y;
  const int qb = blockIdx.x * 64 + wave * 16;
  const int lo = lane & 15, hi4 = lane >> 4;
  const signed char* qg = qi8 + (size_t)g * T_DIM * DH;
  const signed char* kg = ki8 + (size_t)g * T_DIM * DH;
  const signed char* vg = viT8 + (size_t)g * DH * T_DIM;
  const i32x4 qfr = *reinterpret_cast<const i32x4*>(qg + (size_t)(qb + lo) * DH + hi4 * 16);
  const float rz = 1.0f / rowZ[(size_t)g * T_DIM + qb + lo];
  const float crow = rz * inv_sp;
  const float bneg = -rowL[(size_t)g * T_DIM + qb + lo] * a;
  const i32x4 zero = {0, 0, 0, 0};
  i32x4 accv[4];
#pragma unroll
  for (int dt = 0; dt < 4; ++dt) accv[dt] = zero;

  for (int kc = 0; kc < T_DIM; kc += 64) {
    int pk[4];
#pragma unroll
    for (int t = 0; t < 4; ++t) {
      i32x4 kfr =
          *reinterpret_cast<const i32x4*>(kg + (size_t)(kc + t * 16 + lo) * DH + hi4 * 16);
      i32x4 sc = __builtin_amdgcn_mfma_i32_16x16x64_i8(kfr, qfr, zero, 0, 0, 0);
      int ip[4];
#pragma unroll
      for (int r = 0; r < 4; ++r) {
        float lf = rintf((float)sc[r] * ratio);
        float e = exp2f(fmaf(lf, a, bneg));
        float pf = fminf(rintf(e * crow), 127.f);
        ip[r] = (int)pf;
      }
      pk[t] = (ip[0] & 255) | ((ip[1] & 255) << 8) | ((ip[2] & 255) << 16) | (ip[3] << 24);
    }
    xpose4(hi4, pk[0], pk[1], pk[2], pk[3]);
    const i32x4 pfr = {pk[0], pk[1], pk[2], pk[3]};
#pragma unroll
    for (int dt = 0; dt < 4; ++dt) {
      i32x4 vfr =
          *reinterpret_cast<const i32x4*>(vg + (size_t)(dt * 16 + lo) * T_DIM + kc + hi4 * 16);
      accv[dt] = __builtin_amdgcn_mfma_i32_16x16x64_i8(pfr, vfr, accv[dt], 0, 0, 0);
    }
  }
  int am = 0;
#pragma unroll
  for (int dt = 0; dt < 4; ++dt)
#pragma unroll
    for (int r = 0; r < 4; ++r) {
      int v = accv[dt][r];
      attn_out[((size_t)g * T_DIM + qb + hi4 * 4 + r) * DH + dt * 16 + lo] = v;
      int av = v < 0 ? -v : v;
      am = av > am ? av : am;
    }
#pragma unroll
  for (int s = 32; s; s >>= 1) { int o = __shfl_xor(am, s); am = o > am ? o : am; }
  __shared__ int sm;
  if (threadIdx.x == 0) sm = 0;
  __syncthreads();
  if (lane == 0) atomicMax(&sm, am);
  __syncthreads();
  if (threadIdx.x == 0) atomicMax((int*)&scal[5], sm);
}

// ---------- pass4: fake-quant attn, reorder [g][t][dh] -> (t,b,d), split to bf16 hi/lo ----------
__global__ __launch_bounds__(256) void quant_attn_kernel(const int* __restrict__ attn_i32,
                                                         unsigned short* __restrict__ aq_hi,
                                                         unsigned short* __restrict__ aq_lo,
                                                         const unsigned* __restrict__ scal) {
  const float sv = __uint_as_float(scal[2]) / 127.0f + 1e-8f;
  const float maxp = 1.0f / __uint_as_float(scal[4]);
  const float s_p = maxp / 127.0f + 1e-8f;
  const float spsv = s_p * sv;
  const float amax = spsv * (float)(int)scal[5];
  const float s_a = amax / 127.0f + 1e-8f;
  size_t i4 = ((size_t)blockIdx.x * 256 + threadIdx.x) * 4;
  i32x4 iv = *reinterpret_cast<const i32x4*>(attn_i32 + i4);
  int dh0 = (int)(i4 & 63);
  int t = (int)((i4 >> 6) & (T_DIM - 1));
  int g = (int)(i4 >> 17);
  int b = g >> 4, h = g & 15;
  ushort4 hh, ll;
  { float v = (float)iv[0] * spsv; float lf = fminf(127.f, fmaxf(-127.f, rintf(v / s_a)));
    float qv = lf * s_a; hh.x = f32_to_bf16_rne(qv); ll.x = f32_to_bf16_rne(qv - bf16_to_f32(hh.x)); }
  { float v = (float)iv[1] * spsv; float lf = fminf(127.f, fmaxf(-127.f, rintf(v / s_a)));
    float qv = lf * s_a; hh.y = f32_to_bf16_rne(qv); ll.y = f32_to_bf16_rne(qv - bf16_to_f32(hh.y)); }
  { float v = (float)iv[2] * spsv; float lf = fminf(127.f, fmaxf(-127.f, rintf(v / s_a)));
    float qv = lf * s_a; hh.z = f32_to_bf16_rne(qv); ll.z = f32_to_bf16_rne(qv - bf16_to_f32(hh.z)); }
  { float v = (float)iv[3] * spsv; float lf = fminf(127.f, fmaxf(-127.f, rintf(v / s_a)));
    float qv = lf * s_a; hh.w = f32_to_bf16_rne(qv); ll.w = f32_to_bf16_rne(qv - bf16_to_f32(hh.w)); }
  size_t o = (size_t)(t * B_DIM + b) * D_DIM + h * 64 + dh0;
  *reinterpret_cast<ushort4*>(aq_hi + o) = hh;
  *reinterpret_cast<ushort4*>(aq_lo + o) = ll;
}

// ---------------- launch ----------------
extern "C" void kernel_launch(void* const* d_in, const int* in_sizes, int n_in,
                              void* d_out, int out_size, void* d_ws, size_t ws_size,
                              hipStream_t stream) {
  (void)in_sizes; (void)n_in; (void)out_size;
  const float* x  = (const float*)d_in[0];
  const float* wq = (const float*)d_in[1];
  const float* bq = (const float*)d_in[2];
  const float* wk = (const float*)d_in[3];
  const float* bk = (const float*)d_in[4];
  const float* wv = (const float*)d_in[5];
  const float* bv = (const float*)d_in[6];
  const float* wo = (const float*)d_in[7];
  const float* bo = (const float*)d_in[8];
  float* out = (float*)d_out;
  char* ws = (char*)d_ws;

  constexpr size_t SZ_ROW   = (size_t)G_DIM * T_DIM * 4;        // 256 KiB
  constexpr size_t SZ_XSPL  = (size_t)N_ROWS * D_DIM * 2;       // 8 MiB
  constexpr size_t SZ_WSPL  = (size_t)4 * D_DIM * D_DIM * 2;    // 8 MiB
  constexpr size_t SZ_QKV   = (size_t)N_ROWS * 3072 * 4;        // 48 MiB
  constexpr size_t SZ_I8    = (size_t)G_DIM * T_DIM * DH;       // 4 MiB
  constexpr size_t OFF_ROWZ = 256;
  constexpr size_t OFF_ROWL = OFF_ROWZ + SZ_ROW;
  constexpr size_t OFF_XHI  = OFF_ROWL + SZ_ROW;
  constexpr size_t OFF_XLO  = OFF_XHI + SZ_XSPL;
  constexpr size_t OFF_WHI  = OFF_XLO + SZ_XSPL;
  constexpr size_t OFF_WLO  = OFF_WHI + SZ_WSPL;
  constexpr size_t OFF_QKV  = OFF_WLO + SZ_WSPL;
  constexpr size_t OFF_QI8  = OFF_QKV + SZ_QKV;
  constexpr size_t OFF_KI8  = OFF_QI8 + SZ_I8;
  constexpr size_t OFF_VIT8 = OFF_KI8 + SZ_I8;
  constexpr size_t OFF_END  = OFF_VIT8 + SZ_I8;  // ~92.5 MiB (same as round 1)
  if (ws_size < OFF_END) return;

  unsigned* scal = (unsigned*)ws;  // [0]amax_q [1]amax_k [2]amax_v [3]score_absint [4]minZ [5]attn_absint [6]amax_out(dummy)
  float* rowZ = (float*)(ws + OFF_ROWZ);
  float* rowL = (float*)(ws + OFF_ROWL);
  unsigned short* x_hi = (unsigned short*)(ws + OFF_XHI);
  unsigned short* x_lo = (unsigned short*)(ws + OFF_XLO);
  unsigned short* w_hi = (unsigned short*)(ws + OFF_WHI);
  unsigned short* w_lo = (unsigned short*)(ws + OFF_WLO);
  float* qkv32 = (float*)(ws + OFF_QKV);
  signed char* qi8 = (signed char*)(ws + OFF_QI8);
  signed char* ki8 = (signed char*)(ws + OFF_KI8);
  signed char* viT8 = (signed char*)(ws + OFF_VIT8);
  int* attn_i32 = (int*)(ws + OFF_QKV);             // alias: qkv32 dead after quant passes
  unsigned short* aq_hi = x_hi;                     // alias: x splits dead after qkv GEMM
  unsigned short* aq_lo = x_lo;

  hipMemsetAsync(ws, 0, 64, stream);
  split_x_kernel<<<4096, 256, 0, stream>>>(x, x_hi, x_lo);
  split_w_kernel<<<dim3(1024, 1, 4), 256, 0, stream>>>(wq, wk, wv, wo, w_hi, w_lo);
  // fused Q/K/V projection: N=3072 over stacked weights; alpha=0.125 on q section only
  gemm_bf16x3_v2<<<1536, 256, 0, stream>>>(x_hi, x_lo, w_hi, w_lo, bq, bk, bv, qkv32, 3072,
                                           scal, 0.125f);
  quant_qk_kernel<<<dim3(4096, 2), 256, 0, stream>>>(qkv32, qi8, ki8, scal);
  quant_v_kernel<<<dim3(32, 32), 256, 0, stream>>>(qkv32, viT8, scal);
  attn_smax_kernel<<<dim3(32, 32), 256, 0, stream>>>(qi8, ki8, scal);
  attn_stats_kernel<<<dim3(32, 32), 256, 0, stream>>>(qi8, ki8, scal, rowZ, rowL);
  attn_pv_kernel<<<dim3(32, 32), 256, 0, stream>>>(qi8, ki8, viT8, rowZ, rowL, scal, attn_i32);
  quant_attn_kernel<<<4096, 256, 0, stream>>>(attn_i32, aq_hi, aq_lo, scal);
  gemm_bf16x3_v2<<<512, 256, 0, stream>>>(aq_hi, aq_lo, w_hi + 3145728, w_lo + 3145728, bo, bo,
                                          bo, out, 1024, scal + 6, 1.0f);
}

// Round 4
// 429.742 us; speedup vs baseline: 1.3713x; 1.0194x over previous
//
#include <hip/hip_runtime.h>
#include <stdint.h>

#define T_DIM 2048
#define B_DIM 2
#define D_DIM 1024
#define H_DIM 16
#define DH    64
#define G_DIM 32          // B*H
#define N_ROWS 4096       // T*B
#define K_DIM 1024

typedef __bf16 bf16x8 __attribute__((ext_vector_type(8)));
typedef float  f32x4  __attribute__((ext_vector_type(4)));
typedef int    i32x4  __attribute__((ext_vector_type(4)));

typedef const __attribute__((address_space(1))) unsigned int* gas_u32;
typedef __attribute__((address_space(3))) unsigned int* las_u32;

static __device__ __forceinline__ void gload16(const void* gsrc, void* ldst) {
  __builtin_amdgcn_global_load_lds((gas_u32)gsrc, (las_u32)ldst, 16, 0, 0);
}

// ---------- bf16 split helpers (RNE, matches HW bf16 rounding) ----------
static __device__ __forceinline__ unsigned short f32_to_bf16_rne(float f) {
  unsigned u = __float_as_uint(f);
  u += 0x7FFFu + ((u >> 16) & 1u);
  return (unsigned short)(u >> 16);
}
static __device__ __forceinline__ float bf16_to_f32(unsigned short h) {
  return __uint_as_float(((unsigned)h) << 16);
}

static __device__ __forceinline__ void split4_store(const float* __restrict__ src,
                                                    unsigned short* __restrict__ hi,
                                                    unsigned short* __restrict__ lo,
                                                    size_t i4) {
  float4 x = *reinterpret_cast<const float4*>(src + i4);
  ushort4 h, l;
  { float f = x.x; h.x = f32_to_bf16_rne(f); l.x = f32_to_bf16_rne(f - bf16_to_f32(h.x)); }
  { float f = x.y; h.y = f32_to_bf16_rne(f); l.y = f32_to_bf16_rne(f - bf16_to_f32(h.y)); }
  { float f = x.z; h.z = f32_to_bf16_rne(f); l.z = f32_to_bf16_rne(f - bf16_to_f32(h.z)); }
  { float f = x.w; h.w = f32_to_bf16_rne(f); l.w = f32_to_bf16_rne(f - bf16_to_f32(h.w)); }
  *reinterpret_cast<ushort4*>(hi + i4) = h;
  *reinterpret_cast<ushort4*>(lo + i4) = l;
}

__global__ __launch_bounds__(256) void split_x_kernel(const float* __restrict__ src,
                                                      unsigned short* __restrict__ hi,
                                                      unsigned short* __restrict__ lo) {
  size_t i4 = ((size_t)blockIdx.x * 256 + threadIdx.x) * 4;
  split4_store(src, hi, lo, i4);
}

__global__ __launch_bounds__(256) void split_w_kernel(const float* __restrict__ w0,
                                                      const float* __restrict__ w1,
                                                      const float* __restrict__ w2,
                                                      const float* __restrict__ w3,
                                                      unsigned short* __restrict__ hi,
                                                      unsigned short* __restrict__ lo) {
  const int z = blockIdx.z;
  const float* src = (z == 0) ? w0 : (z == 1) ? w1 : (z == 2) ? w2 : w3;
  size_t base = (size_t)z * (D_DIM * D_DIM);
  size_t i4 = ((size_t)blockIdx.x * 256 + threadIdx.x) * 4;
  split4_store(src, hi + base, lo + base, i4);
}

// ---------- bf16x3 GEMM v3: 128x128 tile, LDS-staged, fused multi-section N ----------
// C[M=4096,ncols] = (A[4096,1024] @ Wstack[ncols,1024]^T + bias[sec]) * alpha[sec]
// tile 128x128, BK=64, 4 waves (2x2 of 64x64), grid 1-D, XCD-swizzled.
__global__ __launch_bounds__(256, 2) void gemm_bf16x3_v3(
    const unsigned short* __restrict__ Ahi, const unsigned short* __restrict__ Alo,
    const unsigned short* __restrict__ Whi, const unsigned short* __restrict__ Wlo,
    const float* __restrict__ b0, const float* __restrict__ b1, const float* __restrict__ b2,
    float* __restrict__ C, int ncols, unsigned* __restrict__ scal_base, float alpha0) {
  __shared__ __align__(16) unsigned short sAh[128 * 64];
  __shared__ __align__(16) unsigned short sAl[128 * 64];
  __shared__ __align__(16) unsigned short sWh[128 * 64];
  __shared__ __align__(16) unsigned short sWl[128 * 64];
  __shared__ unsigned sam;
  const int lane = threadIdx.x & 63, wave = threadIdx.x >> 6;
  const int ntn = ncols >> 7;
  const int cpx = gridDim.x >> 3;
  const int bid = blockIdx.x;
  const int swz = (bid & 7) * cpx + (bid >> 3);   // gridDim.x % 8 == 0 always here
  const int tm = swz / ntn, tn = swz - tm * ntn;
  const int rowBase = tm * 128, colBase = tn * 128;
  const int wr = wave >> 1, wc = wave & 1;
  const int lr = lane >> 3, lk = (lane & 7) * 8;
  const int lo = lane & 15, hi4 = lane >> 4;

  f32x4 acc[4][4];
#pragma unroll
  for (int i = 0; i < 4; ++i)
#pragma unroll
    for (int j = 0; j < 4; ++j) acc[i][j] = f32x4{0.f, 0.f, 0.f, 0.f};

  for (int k0 = 0; k0 < K_DIM; k0 += 64) {
    __syncthreads();
#pragma unroll
    for (int i = 0; i < 4; ++i) {
      const int ca = wave * 4 + i;
      const size_t go = (size_t)(rowBase + ca * 8 + lr) * K_DIM + k0 + lk;
      gload16(Ahi + go, &sAh[ca * 512]);
      gload16(Alo + go, &sAl[ca * 512]);
      const size_t gw = (size_t)(colBase + ca * 8 + lr) * K_DIM + k0 + lk;
      gload16(Whi + gw, &sWh[ca * 512]);
      gload16(Wlo + gw, &sWl[ca * 512]);
    }
    __syncthreads();
#pragma unroll
    for (int kk = 0; kk < 64; kk += 32) {
      bf16x8 ah[4], al[4], wh[4], wl[4];
#pragma unroll
      for (int rt = 0; rt < 4; ++rt) {
        const int offA = (wr * 64 + rt * 16 + lo) * 64 + kk + hi4 * 8;
        ah[rt] = *reinterpret_cast<const bf16x8*>(&sAh[offA]);
        al[rt] = *reinterpret_cast<const bf16x8*>(&sAl[offA]);
        const int offW = (wc * 64 + rt * 16 + lo) * 64 + kk + hi4 * 8;
        wh[rt] = *reinterpret_cast<const bf16x8*>(&sWh[offW]);
        wl[rt] = *reinterpret_cast<const bf16x8*>(&sWl[offW]);
      }
      // pass-outermost: 16 independent MFMAs between dependent acc reuses
#pragma unroll
      for (int jt = 0; jt < 4; ++jt)
#pragma unroll
        for (int rt = 0; rt < 4; ++rt)
          acc[rt][jt] = __builtin_amdgcn_mfma_f32_16x16x32_bf16(ah[rt], wh[jt], acc[rt][jt], 0, 0, 0);
#pragma unroll
      for (int jt = 0; jt < 4; ++jt)
#pragma unroll
        for (int rt = 0; rt < 4; ++rt)
          acc[rt][jt] = __builtin_amdgcn_mfma_f32_16x16x32_bf16(ah[rt], wl[jt], acc[rt][jt], 0, 0, 0);
#pragma unroll
      for (int jt = 0; jt < 4; ++jt)
#pragma unroll
        for (int rt = 0; rt < 4; ++rt)
          acc[rt][jt] = __builtin_amdgcn_mfma_f32_16x16x32_bf16(al[rt], wh[jt], acc[rt][jt], 0, 0, 0);
    }
  }
  // epilogue: bias + alpha per section (128-tiles never straddle 1024-sections), store, absmax
  const int sec = colBase >> 10;
  const float* bp = (sec == 0) ? b0 : ((sec == 1) ? b1 : b2);
  const float alpha = (sec == 0) ? alpha0 : 1.0f;
  const int colL = (colBase & 1023) + wc * 64;
  float bj[4];
#pragma unroll
  for (int jt = 0; jt < 4; ++jt) bj[jt] = bp[colL + jt * 16 + lo];
  float am = 0.f;
#pragma unroll
  for (int rt = 0; rt < 4; ++rt)
#pragma unroll
    for (int jt = 0; jt < 4; ++jt)
#pragma unroll
      for (int r = 0; r < 4; ++r) {
        float v = (acc[rt][jt][r] + bj[jt]) * alpha;
        C[(size_t)(rowBase + wr * 64 + rt * 16 + hi4 * 4 + r) * ncols + colBase + wc * 64 +
          jt * 16 + lo] = v;
        am = fmaxf(am, fabsf(v));
      }
#pragma unroll
  for (int s = 32; s; s >>= 1) am = fmaxf(am, __shfl_xor(am, s));
  if (threadIdx.x == 0) sam = 0u;
  __syncthreads();
  if (lane == 0) atomicMax(&sam, __float_as_uint(am));
  __syncthreads();
  if (threadIdx.x == 0) atomicMax(scal_base + sec, sam);
}

// ---------- quantize q,k into [g][t][dh] int8 (also inits minZ scalar) ----------
__global__ __launch_bounds__(256) void quant_qk_kernel(const float* __restrict__ qkv32,
                                                       signed char* __restrict__ qi8,
                                                       signed char* __restrict__ ki8,
                                                       unsigned* __restrict__ scal) {
  if (blockIdx.x == 0 && blockIdx.y == 0 && threadIdx.x == 0) scal[4] = 0x7F800000u;  // minZ=+inf
  const int which = blockIdx.y;
  signed char* dst = which ? ki8 : qi8;
  const float s = __uint_as_float(scal[which]) / 127.0f + 1e-8f;
  size_t i4 = ((size_t)blockIdx.x * 256 + threadIdx.x) * 4;
  int d = (int)(i4 & (D_DIM - 1));
  int row = (int)(i4 >> 10);
  float4 x = *reinterpret_cast<const float4*>(qkv32 + (size_t)row * 3072 + which * 1024 + d);
  int t = row >> 1, b = row & 1;
  int h = d >> 6, dh = d & 63;
  char4 c;
  { float q = rintf(x.x / s); q = fminf(127.f, fmaxf(-127.f, q)); c.x = (signed char)q; }
  { float q = rintf(x.y / s); q = fminf(127.f, fmaxf(-127.f, q)); c.y = (signed char)q; }
  { float q = rintf(x.z / s); q = fminf(127.f, fmaxf(-127.f, q)); c.z = (signed char)q; }
  { float q = rintf(x.w / s); q = fminf(127.f, fmaxf(-127.f, q)); c.w = (signed char)q; }
  *reinterpret_cast<char4*>(dst + (((size_t)(b * H_DIM + h) * T_DIM + t) * DH + dh)) = c;
}

// ---------- quantize v and transpose to [g][dh][t] int8 ----------
__global__ __launch_bounds__(256) void quant_v_kernel(const float* __restrict__ qkv32,
                                                      signed char* __restrict__ viT8,
                                                      const unsigned* __restrict__ scal) {
  const float s = __uint_as_float(scal[2]) / 127.0f + 1e-8f;
  const int g = blockIdx.y, t0 = blockIdx.x * 64;
  const int b = g >> 4, h = g & 15;
  __shared__ signed char tile[64][68];
  const int tid = threadIdx.x;
#pragma unroll
  for (int rep = 0; rep < 4; ++rep) {
    int tl = tid >> 2;
    int f4 = (tid & 3) + rep * 4;
    const float* p = qkv32 + ((size_t)(t0 + tl) * B_DIM + b) * 3072 + 2048 + h * 64 + f4 * 4;
    float4 x = *reinterpret_cast<const float4*>(p);
    char4 c;
    { float q = rintf(x.x / s); q = fminf(127.f, fmaxf(-127.f, q)); c.x = (signed char)q; }
    { float q = rintf(x.y / s); q = fminf(127.f, fmaxf(-127.f, q)); c.y = (signed char)q; }
    { float q = rintf(x.z / s); q = fminf(127.f, fmaxf(-127.f, q)); c.z = (signed char)q; }
    { float q = rintf(x.w / s); q = fminf(127.f, fmaxf(-127.f, q)); c.w = (signed char)q; }
    *reinterpret_cast<char4*>(&tile[tl][f4 * 4]) = c;
  }
  __syncthreads();
  const int dh = tid >> 2, tq = tid & 3;
  signed char outb[16];
#pragma unroll
  for (int j = 0; j < 16; ++j) outb[j] = tile[tq * 16 + j][dh];
  i32x4 vv;
  __builtin_memcpy(&vv, outb, 16);
  *reinterpret_cast<i32x4*>(viT8 + ((size_t)g * DH + dh) * T_DIM + t0 + tq * 16) = vv;
}

// ---------- in-register 4x4 dword transpose across lanes {lo, lo+16, lo+32, lo+48} ----------
static __device__ __forceinline__ void xpose4(int h, int& p0, int& p1, int& p2, int& p3) {
  const bool b0 = (h & 1), b1 = (h & 2);
  int s0 = __shfl_xor(p0, 16), s1 = __shfl_xor(p1, 16);
  int s2 = __shfl_xor(p2, 16), s3 = __shfl_xor(p3, 16);
  int q0 = b0 ? s1 : p0;
  int q1 = b0 ? p1 : s0;
  int q2 = b0 ? s3 : p2;
  int q3 = b0 ? p3 : s2;
  int u0 = __shfl_xor(q0, 32), u1 = __shfl_xor(q1, 32);
  int u2 = __shfl_xor(q2, 32), u3 = __shfl_xor(q3, 32);
  p0 = b1 ? u2 : q0;
  p1 = b1 ? u3 : q1;
  p2 = b1 ? q2 : u0;
  p3 = b1 ? q3 : u1;
}

// ---------- pass1: global max|idot| over all scores (swapped mfma(K,Q)) ----------
__global__ __launch_bounds__(256) void attn_smax_kernel(const signed char* __restrict__ qi8,
                                                        const signed char* __restrict__ ki8,
                                                        unsigned* __restrict__ scal) {
  const int lane = threadIdx.x & 63, wave = threadIdx.x >> 6;
  const int g = blockIdx.y;
  const int qb = blockIdx.x * 64 + wave * 16;
  const int lo = lane & 15, hi4 = lane >> 4;
  const signed char* qg = qi8 + (size_t)g * T_DIM * DH;
  const signed char* kg = ki8 + (size_t)g * T_DIM * DH;
  const i32x4 qfr = *reinterpret_cast<const i32x4*>(qg + (size_t)(qb + lo) * DH + hi4 * 16);
  const i32x4 zero = {0, 0, 0, 0};
  int mx = -2147483647, mn = 2147483647;
#pragma unroll 4
  for (int kc = 0; kc < T_DIM; kc += 16) {
    i32x4 kfr = *reinterpret_cast<const i32x4*>(kg + (size_t)(kc + lo) * DH + hi4 * 16);
    i32x4 sc = __builtin_amdgcn_mfma_i32_16x16x64_i8(kfr, qfr, zero, 0, 0, 0);
#pragma unroll
    for (int r = 0; r < 4; ++r) { mx = sc[r] > mx ? sc[r] : mx; mn = sc[r] < mn ? sc[r] : mn; }
  }
  int am = mx > -mn ? mx : -mn;
#pragma unroll
  for (int s = 32; s; s >>= 1) { int o = __shfl_xor(am, s); am = o > am ? o : am; }
  __shared__ int sm;
  if (threadIdx.x == 0) sm = 0;
  __syncthreads();
  if (lane == 0) atomicMax(&sm, am);
  __syncthreads();
  if (threadIdx.x == 0) atomicMax((int*)&scal[3], sm);
}

// ---------- pass2: per-row lmax & Z via LDS exp-LUT (lf integer in [-127,127]) ----------
__global__ __launch_bounds__(256) void attn_stats_kernel(const signed char* __restrict__ qi8,
                                                         const signed char* __restrict__ ki8,
                                                         unsigned* __restrict__ scal,
                                                         float* __restrict__ rowZ,
                                                         float* __restrict__ rowL) {
  const float sq = __uint_as_float(scal[0]) / 127.0f + 1e-8f;
  const float sk = __uint_as_float(scal[1]) / 127.0f + 1e-8f;
  const float sqsk = sq * sk;
  const float smax = sqsk * (float)(int)scal[3];
  const float s_s = smax / 127.0f + 1e-8f;
  const float ratio = sqsk / s_s;
  const float a = s_s * 1.4426950408889634f;   // s_s * log2(e)
  const float c = -127.0f * a;
  __shared__ float gLut[256];
  const int tid = threadIdx.x;
  if (tid < 255) gLut[tid] = exp2f(fmaf((float)(tid - 127), a, c));  // same fp ops as before
  __syncthreads();
  const int lane = tid & 63, wave = tid >> 6;
  const int g = blockIdx.y;
  const int qb = blockIdx.x * 64 + wave * 16;
  const int lo = lane & 15, hi4 = lane >> 4;
  const signed char* qg = qi8 + (size_t)g * T_DIM * DH;
  const signed char* kg = ki8 + (size_t)g * T_DIM * DH;
  const i32x4 qfr = *reinterpret_cast<const i32x4*>(qg + (size_t)(qb + lo) * DH + hi4 * 16);
  const i32x4 zero = {0, 0, 0, 0};
  int scmax = -2147483647;
  float zp = 0.f;
#pragma unroll 4
  for (int kc = 0; kc < T_DIM; kc += 16) {
    i32x4 kfr = *reinterpret_cast<const i32x4*>(kg + (size_t)(kc + lo) * DH + hi4 * 16);
    i32x4 sc = __builtin_amdgcn_mfma_i32_16x16x64_i8(kfr, qfr, zero, 0, 0, 0);
#pragma unroll
    for (int r = 0; r < 4; ++r) {
      scmax = sc[r] > scmax ? sc[r] : scmax;
      int idx = (int)rintf((float)sc[r] * ratio) + 127;
      zp += gLut[idx];
    }
  }
  // cross-lane reduce over the 4 hi4 groups (each handled 512 k's for row qb+lo)
  { int o = __shfl_xor(scmax, 16); scmax = o > scmax ? o : scmax; }
  zp += __shfl_xor(zp, 16);
  { int o = __shfl_xor(scmax, 32); scmax = o > scmax ? o : scmax; }
  zp += __shfl_xor(zp, 32);
  float mx = rintf((float)scmax * ratio);      // rint is monotone: max(rint)=rint(max)
  float Z = zp * exp2f((127.0f - mx) * a);     // true softmax denom, <= 2048
  if (hi4 == 0) {
    rowZ[(size_t)g * T_DIM + qb + lo] = Z;
    rowL[(size_t)g * T_DIM + qb + lo] = mx;
  }
  float zm = Z;
#pragma unroll
  for (int s = 32; s; s >>= 1) zm = fminf(zm, __shfl_xor(zm, s));
  __shared__ unsigned szm;
  if (tid == 0) szm = 0x7F800000u;
  __syncthreads();
  if (lane == 0) atomicMin(&szm, __float_as_uint(zm));
  __syncthreads();
  if (tid == 0) atomicMin(&scal[4], szm);
}

// ---------- pass3: swapped QK -> per-row byte-LUT P-quant -> shfl-transpose -> PV ----------
#define LUTS 260   // row stride (bytes); 65 dwords, odd -> uniform-idx reads spread banks
__global__ __launch_bounds__(256) void attn_pv_kernel(const signed char* __restrict__ qi8,
                                                      const signed char* __restrict__ ki8,
                                                      const signed char* __restrict__ viT8,
                                                      const float* __restrict__ rowZ,
                                                      const float* __restrict__ rowL,
                                                      unsigned* __restrict__ scal,
                                                      int* __restrict__ attn_out) {
  const float sq = __uint_as_float(scal[0]) / 127.0f + 1e-8f;
  const float sk = __uint_as_float(scal[1]) / 127.0f + 1e-8f;
  const float sqsk = sq * sk;
  const float smax = sqsk * (float)(int)scal[3];
  const float s_s = smax / 127.0f + 1e-8f;
  const float ratio = sqsk / s_s;
  const float a = s_s * 1.4426950408889634f;
  const float maxp = 1.0f / __uint_as_float(scal[4]);
  const float s_p = maxp / 127.0f + 1e-8f;
  const float inv_sp = 1.0f / s_p;
  const int tid = threadIdx.x;
  const int lane = tid & 63, wave = tid >> 6;
  const int g = blockIdx.y;
  const int qb0 = blockIdx.x * 64;
  const int qb = qb0 + wave * 16;
  const int lo = lane & 15, hi4 = lane >> 4;

  // ---- per-row byte LUT: plut[row][i] = quantized prob byte for lf = i-127 ----
  __shared__ signed char plut[64 * LUTS];
  for (int n = tid; n < 64 * 256; n += 256) {
    const int row = n >> 8, i = n & 255;
    if (i < 255) {
      const float Zr = rowZ[(size_t)g * T_DIM + qb0 + row];
      const float lm = rowL[(size_t)g * T_DIM + qb0 + row];
      const float crow = (1.0f / Zr) * inv_sp;
      const float bneg = -lm * a;
      const float lf = (float)(i - 127);
      const float e = exp2f(fmaf(lf, a, bneg));
      const float pf = fminf(rintf(e * crow), 127.f);
      plut[row * LUTS + i] = (signed char)(int)pf;
    }
  }
  __syncthreads();

  const signed char* qg = qi8 + (size_t)g * T_DIM * DH;
  const signed char* kg = ki8 + (size_t)g * T_DIM * DH;
  const signed char* vg = viT8 + (size_t)g * DH * T_DIM;
  const i32x4 qfr = *reinterpret_cast<const i32x4*>(qg + (size_t)(qb + lo) * DH + hi4 * 16);
  const int lbase = (wave * 16 + lo) * LUTS + 127;   // per-lane LUT base (row fixed per lane)
  const i32x4 zero = {0, 0, 0, 0};
  i32x4 accv[4];
#pragma unroll
  for (int dt = 0; dt < 4; ++dt) accv[dt] = zero;

  for (int kc = 0; kc < T_DIM; kc += 64) {
    int pk[4];
#pragma unroll
    for (int t = 0; t < 4; ++t) {
      i32x4 kfr =
          *reinterpret_cast<const i32x4*>(kg + (size_t)(kc + t * 16 + lo) * DH + hi4 * 16);
      i32x4 sc = __builtin_amdgcn_mfma_i32_16x16x64_i8(kfr, qfr, zero, 0, 0, 0);
      unsigned b0, b1, b2, b3;
      { int idx = (int)rintf((float)sc[0] * ratio); b0 = (unsigned char)plut[lbase + idx]; }
      { int idx = (int)rintf((float)sc[1] * ratio); b1 = (unsigned char)plut[lbase + idx]; }
      { int idx = (int)rintf((float)sc[2] * ratio); b2 = (unsigned char)plut[lbase + idx]; }
      { int idx = (int)rintf((float)sc[3] * ratio); b3 = (unsigned char)plut[lbase + idx]; }
      pk[t] = (int)(b0 | (b1 << 8) | (b2 << 16) | (b3 << 24));
    }
    xpose4(hi4, pk[0], pk[1], pk[2], pk[3]);
    const i32x4 pfr = {pk[0], pk[1], pk[2], pk[3]};
#pragma unroll
    for (int dt = 0; dt < 4; ++dt) {
      i32x4 vfr =
          *reinterpret_cast<const i32x4*>(vg + (size_t)(dt * 16 + lo) * T_DIM + kc + hi4 * 16);
      accv[dt] = __builtin_amdgcn_mfma_i32_16x16x64_i8(pfr, vfr, accv[dt], 0, 0, 0);
    }
  }
  int am = 0;
#pragma unroll
  for (int dt = 0; dt < 4; ++dt)
#pragma unroll
    for (int r = 0; r < 4; ++r) {
      int v = accv[dt][r];
      attn_out[((size_t)g * T_DIM + qb + hi4 * 4 + r) * DH + dt * 16 + lo] = v;
      int av = v < 0 ? -v : v;
      am = av > am ? av : am;
    }
#pragma unroll
  for (int s = 32; s; s >>= 1) { int o = __shfl_xor(am, s); am = o > am ? o : am; }
  __shared__ int sm;
  if (tid == 0) sm = 0;
  __syncthreads();
  if (lane == 0) atomicMax(&sm, am);
  __syncthreads();
  if (tid == 0) atomicMax((int*)&scal[5], sm);
}

// ---------- pass4: fake-quant attn, reorder [g][t][dh] -> (t,b,d), split to bf16 hi/lo ----------
__global__ __launch_bounds__(256) void quant_attn_kernel(const int* __restrict__ attn_i32,
                                                         unsigned short* __restrict__ aq_hi,
                                                         unsigned short* __restrict__ aq_lo,
                                                         const unsigned* __restrict__ scal) {
  const float sv = __uint_as_float(scal[2]) / 127.0f + 1e-8f;
  const float maxp = 1.0f / __uint_as_float(scal[4]);
  const float s_p = maxp / 127.0f + 1e-8f;
  const float spsv = s_p * sv;
  const float amax = spsv * (float)(int)scal[5];
  const float s_a = amax / 127.0f + 1e-8f;
  size_t i4 = ((size_t)blockIdx.x * 256 + threadIdx.x) * 4;
  i32x4 iv = *reinterpret_cast<const i32x4*>(attn_i32 + i4);
  int dh0 = (int)(i4 & 63);
  int t = (int)((i4 >> 6) & (T_DIM - 1));
  int g = (int)(i4 >> 17);
  int b = g >> 4, h = g & 15;
  ushort4 hh, ll;
  { float v = (float)iv[0] * spsv; float lf = fminf(127.f, fmaxf(-127.f, rintf(v / s_a)));
    float qv = lf * s_a; hh.x = f32_to_bf16_rne(qv); ll.x = f32_to_bf16_rne(qv - bf16_to_f32(hh.x)); }
  { float v = (float)iv[1] * spsv; float lf = fminf(127.f, fmaxf(-127.f, rintf(v / s_a)));
    float qv = lf * s_a; hh.y = f32_to_bf16_rne(qv); ll.y = f32_to_bf16_rne(qv - bf16_to_f32(hh.y)); }
  { float v = (float)iv[2] * spsv; float lf = fminf(127.f, fmaxf(-127.f, rintf(v / s_a)));
    float qv = lf * s_a; hh.z = f32_to_bf16_rne(qv); ll.z = f32_to_bf16_rne(qv - bf16_to_f32(hh.z)); }
  { float v = (float)iv[3] * spsv; float lf = fminf(127.f, fmaxf(-127.f, rintf(v / s_a)));
    float qv = lf * s_a; hh.w = f32_to_bf16_rne(qv); ll.w = f32_to_bf16_rne(qv - bf16_to_f32(hh.w)); }
  size_t o = (size_t)(t * B_DIM + b) * D_DIM + h * 64 + dh0;
  *reinterpret_cast<ushort4*>(aq_hi + o) = hh;
  *reinterpret_cast<ushort4*>(aq_lo + o) = ll;
}

// ---------------- launch ----------------
extern "C" void kernel_launch(void* const* d_in, const int* in_sizes, int n_in,
                              void* d_out, int out_size, void* d_ws, size_t ws_size,
                              hipStream_t stream) {
  (void)in_sizes; (void)n_in; (void)out_size;
  const float* x  = (const float*)d_in[0];
  const float* wq = (const float*)d_in[1];
  const float* bq = (const float*)d_in[2];
  const float* wk = (const float*)d_in[3];
  const float* bk = (const float*)d_in[4];
  const float* wv = (const float*)d_in[5];
  const float* bv = (const float*)d_in[6];
  const float* wo = (const float*)d_in[7];
  const float* bo = (const float*)d_in[8];
  float* out = (float*)d_out;
  char* ws = (char*)d_ws;

  constexpr size_t SZ_ROW   = (size_t)G_DIM * T_DIM * 4;        // 256 KiB
  constexpr size_t SZ_XSPL  = (size_t)N_ROWS * D_DIM * 2;       // 8 MiB
  constexpr size_t SZ_WSPL  = (size_t)4 * D_DIM * D_DIM * 2;    // 8 MiB
  constexpr size_t SZ_QKV   = (size_t)N_ROWS * 3072 * 4;        // 48 MiB
  constexpr size_t SZ_I8    = (size_t)G_DIM * T_DIM * DH;       // 4 MiB
  constexpr size_t OFF_ROWZ = 256;
  constexpr size_t OFF_ROWL = OFF_ROWZ + SZ_ROW;
  constexpr size_t OFF_XHI  = OFF_ROWL + SZ_ROW;
  constexpr size_t OFF_XLO  = OFF_XHI + SZ_XSPL;
  constexpr size_t OFF_WHI  = OFF_XLO + SZ_XSPL;
  constexpr size_t OFF_WLO  = OFF_WHI + SZ_WSPL;
  constexpr size_t OFF_QKV  = OFF_WLO + SZ_WSPL;
  constexpr size_t OFF_QI8  = OFF_QKV + SZ_QKV;
  constexpr size_t OFF_KI8  = OFF_QI8 + SZ_I8;
  constexpr size_t OFF_VIT8 = OFF_KI8 + SZ_I8;
  constexpr size_t OFF_END  = OFF_VIT8 + SZ_I8;  // ~92.5 MiB
  if (ws_size < OFF_END) return;

  unsigned* scal = (unsigned*)ws;  // [0]amax_q [1]amax_k [2]amax_v [3]score_absint [4]minZ [5]attn_absint [6]amax_out(dummy)
  float* rowZ = (float*)(ws + OFF_ROWZ);
  float* rowL = (float*)(ws + OFF_ROWL);
  unsigned short* x_hi = (unsigned short*)(ws + OFF_XHI);
  unsigned short* x_lo = (unsigned short*)(ws + OFF_XLO);
  unsigned short* w_hi = (unsigned short*)(ws + OFF_WHI);
  unsigned short* w_lo = (unsigned short*)(ws + OFF_WLO);
  float* qkv32 = (float*)(ws + OFF_QKV);
  signed char* qi8 = (signed char*)(ws + OFF_QI8);
  signed char* ki8 = (signed char*)(ws + OFF_KI8);
  signed char* viT8 = (signed char*)(ws + OFF_VIT8);
  int* attn_i32 = (int*)(ws + OFF_QKV);             // alias: qkv32 dead after quant passes
  unsigned short* aq_hi = x_hi;                     // alias: x splits dead after qkv GEMM
  unsigned short* aq_lo = x_lo;

  hipMemsetAsync(ws, 0, 64, stream);
  split_x_kernel<<<4096, 256, 0, stream>>>(x, x_hi, x_lo);
  split_w_kernel<<<dim3(1024, 1, 4), 256, 0, stream>>>(wq, wk, wv, wo, w_hi, w_lo);
  // fused Q/K/V projection: N=3072 over stacked weights; alpha=0.125 on q section only
  gemm_bf16x3_v3<<<768, 256, 0, stream>>>(x_hi, x_lo, w_hi, w_lo, bq, bk, bv, qkv32, 3072,
                                          scal, 0.125f);
  quant_qk_kernel<<<dim3(4096, 2), 256, 0, stream>>>(qkv32, qi8, ki8, scal);
  quant_v_kernel<<<dim3(32, 32), 256, 0, stream>>>(qkv32, viT8, scal);
  attn_smax_kernel<<<dim3(32, 32), 256, 0, stream>>>(qi8, ki8, scal);
  attn_stats_kernel<<<dim3(32, 32), 256, 0, stream>>>(qi8, ki8, scal, rowZ, rowL);
  attn_pv_kernel<<<dim3(32, 32), 256, 0, stream>>>(qi8, ki8, viT8, rowZ, rowL, scal, attn_i32);
  quant_attn_kernel<<<4096, 256, 0, stream>>>(attn_i32, aq_hi, aq_lo, scal);
  gemm_bf16x3_v3<<<256, 256, 0, stream>>>(aq_hi, aq_lo, w_hi + 3145728, w_lo + 3145728, bo, bo,
                                          bo, out, 1024, scal + 6, 1.0f);
}

// Round 6
// 416.031 us; speedup vs baseline: 1.4165x; 1.0330x over previous
//
#include <hip/hip_runtime.h>
#include <stdint.h>

#define T_DIM 2048
#define B_DIM 2
#define D_DIM 1024
#define H_DIM 16
#define DH    64
#define G_DIM 32          // B*H
#define N_ROWS 4096       // T*B
#define K_DIM 1024

typedef __bf16 bf16x8 __attribute__((ext_vector_type(8)));
typedef float  f32x4  __attribute__((ext_vector_type(4)));
typedef int    i32x4  __attribute__((ext_vector_type(4)));

typedef const __attribute__((address_space(1))) unsigned int* gas_u32;
typedef __attribute__((address_space(3))) unsigned int* las_u32;

static __device__ __forceinline__ void gload16(const void* gsrc, void* ldst) {
  __builtin_amdgcn_global_load_lds((gas_u32)gsrc, (las_u32)ldst, 16, 0, 0);
}

// ---------- bf16 split helpers (RNE, matches HW bf16 rounding) ----------
static __device__ __forceinline__ unsigned short f32_to_bf16_rne(float f) {
  unsigned u = __float_as_uint(f);
  u += 0x7FFFu + ((u >> 16) & 1u);
  return (unsigned short)(u >> 16);
}
static __device__ __forceinline__ float bf16_to_f32(unsigned short h) {
  return __uint_as_float(((unsigned)h) << 16);
}

static __device__ __forceinline__ void split4_store(const float* __restrict__ src,
                                                    unsigned short* __restrict__ hi,
                                                    unsigned short* __restrict__ lo,
                                                    size_t i4) {
  float4 x = *reinterpret_cast<const float4*>(src + i4);
  ushort4 h, l;
  { float f = x.x; h.x = f32_to_bf16_rne(f); l.x = f32_to_bf16_rne(f - bf16_to_f32(h.x)); }
  { float f = x.y; h.y = f32_to_bf16_rne(f); l.y = f32_to_bf16_rne(f - bf16_to_f32(h.y)); }
  { float f = x.z; h.z = f32_to_bf16_rne(f); l.z = f32_to_bf16_rne(f - bf16_to_f32(h.z)); }
  { float f = x.w; h.w = f32_to_bf16_rne(f); l.w = f32_to_bf16_rne(f - bf16_to_f32(h.w)); }
  *reinterpret_cast<ushort4*>(hi + i4) = h;
  *reinterpret_cast<ushort4*>(lo + i4) = l;
}

__global__ __launch_bounds__(256) void split_x_kernel(const float* __restrict__ src,
                                                      unsigned short* __restrict__ hi,
                                                      unsigned short* __restrict__ lo) {
  size_t i4 = ((size_t)blockIdx.x * 256 + threadIdx.x) * 4;
  split4_store(src, hi, lo, i4);
}

__global__ __launch_bounds__(256) void split_w_kernel(const float* __restrict__ w0,
                                                      const float* __restrict__ w1,
                                                      const float* __restrict__ w2,
                                                      const float* __restrict__ w3,
                                                      unsigned short* __restrict__ hi,
                                                      unsigned short* __restrict__ lo) {
  const int z = blockIdx.z;
  const float* src = (z == 0) ? w0 : (z == 1) ? w1 : (z == 2) ? w2 : w3;
  size_t base = (size_t)z * (D_DIM * D_DIM);
  size_t i4 = ((size_t)blockIdx.x * 256 + threadIdx.x) * 4;
  split4_store(src, hi + base, lo + base, i4);
}

// ---------- bf16x3 GEMM v3: 128x128 tile, LDS-staged, fused multi-section N ----------
__global__ __launch_bounds__(256, 2) void gemm_bf16x3_v3(
    const unsigned short* __restrict__ Ahi, const unsigned short* __restrict__ Alo,
    const unsigned short* __restrict__ Whi, const unsigned short* __restrict__ Wlo,
    const float* __restrict__ b0, const float* __restrict__ b1, const float* __restrict__ b2,
    float* __restrict__ C, int ncols, unsigned* __restrict__ scal_base, float alpha0) {
  __shared__ __align__(16) unsigned short sAh[128 * 64];
  __shared__ __align__(16) unsigned short sAl[128 * 64];
  __shared__ __align__(16) unsigned short sWh[128 * 64];
  __shared__ __align__(16) unsigned short sWl[128 * 64];
  __shared__ unsigned sam;
  const int lane = threadIdx.x & 63, wave = threadIdx.x >> 6;
  const int ntn = ncols >> 7;
  const int cpx = gridDim.x >> 3;
  const int bid = blockIdx.x;
  const int swz = (bid & 7) * cpx + (bid >> 3);   // gridDim.x % 8 == 0 always here
  const int tm = swz / ntn, tn = swz - tm * ntn;
  const int rowBase = tm * 128, colBase = tn * 128;
  const int wr = wave >> 1, wc = wave & 1;
  const int lr = lane >> 3, lk = (lane & 7) * 8;
  const int lo = lane & 15, hi4 = lane >> 4;

  f32x4 acc[4][4];
#pragma unroll
  for (int i = 0; i < 4; ++i)
#pragma unroll
    for (int j = 0; j < 4; ++j) acc[i][j] = f32x4{0.f, 0.f, 0.f, 0.f};

  for (int k0 = 0; k0 < K_DIM; k0 += 64) {
    __syncthreads();
#pragma unroll
    for (int i = 0; i < 4; ++i) {
      const int ca = wave * 4 + i;
      const size_t go = (size_t)(rowBase + ca * 8 + lr) * K_DIM + k0 + lk;
      gload16(Ahi + go, &sAh[ca * 512]);
      gload16(Alo + go, &sAl[ca * 512]);
      const size_t gw = (size_t)(colBase + ca * 8 + lr) * K_DIM + k0 + lk;
      gload16(Whi + gw, &sWh[ca * 512]);
      gload16(Wlo + gw, &sWl[ca * 512]);
    }
    __syncthreads();
#pragma unroll
    for (int kk = 0; kk < 64; kk += 32) {
      bf16x8 ah[4], al[4], wh[4], wl[4];
#pragma unroll
      for (int rt = 0; rt < 4; ++rt) {
        const int offA = (wr * 64 + rt * 16 + lo) * 64 + kk + hi4 * 8;
        ah[rt] = *reinterpret_cast<const bf16x8*>(&sAh[offA]);
        al[rt] = *reinterpret_cast<const bf16x8*>(&sAl[offA]);
        const int offW = (wc * 64 + rt * 16 + lo) * 64 + kk + hi4 * 8;
        wh[rt] = *reinterpret_cast<const bf16x8*>(&sWh[offW]);
        wl[rt] = *reinterpret_cast<const bf16x8*>(&sWl[offW]);
      }
#pragma unroll
      for (int jt = 0; jt < 4; ++jt)
#pragma unroll
        for (int rt = 0; rt < 4; ++rt)
          acc[rt][jt] = __builtin_amdgcn_mfma_f32_16x16x32_bf16(ah[rt], wh[jt], acc[rt][jt], 0, 0, 0);
#pragma unroll
      for (int jt = 0; jt < 4; ++jt)
#pragma unroll
        for (int rt = 0; rt < 4; ++rt)
          acc[rt][jt] = __builtin_amdgcn_mfma_f32_16x16x32_bf16(ah[rt], wl[jt], acc[rt][jt], 0, 0, 0);
#pragma unroll
      for (int jt = 0; jt < 4; ++jt)
#pragma unroll
        for (int rt = 0; rt < 4; ++rt)
          acc[rt][jt] = __builtin_amdgcn_mfma_f32_16x16x32_bf16(al[rt], wh[jt], acc[rt][jt], 0, 0, 0);
    }
  }
  const int sec = colBase >> 10;
  const float* bp = (sec == 0) ? b0 : ((sec == 1) ? b1 : b2);
  const float alpha = (sec == 0) ? alpha0 : 1.0f;
  const int colL = (colBase & 1023) + wc * 64;
  float bj[4];
#pragma unroll
  for (int jt = 0; jt < 4; ++jt) bj[jt] = bp[colL + jt * 16 + lo];
  float am = 0.f;
#pragma unroll
  for (int rt = 0; rt < 4; ++rt)
#pragma unroll
    for (int jt = 0; jt < 4; ++jt)
#pragma unroll
      for (int r = 0; r < 4; ++r) {
        float v = (acc[rt][jt][r] + bj[jt]) * alpha;
        C[(size_t)(rowBase + wr * 64 + rt * 16 + hi4 * 4 + r) * ncols + colBase + wc * 64 +
          jt * 16 + lo] = v;
        am = fmaxf(am, fabsf(v));
      }
#pragma unroll
  for (int s = 32; s; s >>= 1) am = fmaxf(am, __shfl_xor(am, s));
  if (threadIdx.x == 0) sam = 0u;
  __syncthreads();
  if (lane == 0) atomicMax(&sam, __float_as_uint(am));
  __syncthreads();
  if (threadIdx.x == 0) atomicMax(scal_base + sec, sam);
}

// ---------- quantize q,k into [g][t][dh] int8 (also inits minZ scalar) ----------
__global__ __launch_bounds__(256) void quant_qk_kernel(const float* __restrict__ qkv32,
                                                       signed char* __restrict__ qi8,
                                                       signed char* __restrict__ ki8,
                                                       unsigned* __restrict__ scal) {
  if (blockIdx.x == 0 && blockIdx.y == 0 && threadIdx.x == 0) scal[4] = 0x7F800000u;  // minZ=+inf
  const int which = blockIdx.y;
  signed char* dst = which ? ki8 : qi8;
  const float s = __uint_as_float(scal[which]) / 127.0f + 1e-8f;
  size_t i4 = ((size_t)blockIdx.x * 256 + threadIdx.x) * 4;
  int d = (int)(i4 & (D_DIM - 1));
  int row = (int)(i4 >> 10);
  float4 x = *reinterpret_cast<const float4*>(qkv32 + (size_t)row * 3072 + which * 1024 + d);
  int t = row >> 1, b = row & 1;
  int h = d >> 6, dh = d & 63;
  char4 c;
  { float q = rintf(x.x / s); q = fminf(127.f, fmaxf(-127.f, q)); c.x = (signed char)q; }
  { float q = rintf(x.y / s); q = fminf(127.f, fmaxf(-127.f, q)); c.y = (signed char)q; }
  { float q = rintf(x.z / s); q = fminf(127.f, fmaxf(-127.f, q)); c.z = (signed char)q; }
  { float q = rintf(x.w / s); q = fminf(127.f, fmaxf(-127.f, q)); c.w = (signed char)q; }
  *reinterpret_cast<char4*>(dst + (((size_t)(b * H_DIM + h) * T_DIM + t) * DH + dh)) = c;
}

// ---------- quantize v and transpose to [g][dh][t] int8 ----------
__global__ __launch_bounds__(256) void quant_v_kernel(const float* __restrict__ qkv32,
                                                      signed char* __restrict__ viT8,
                                                      const unsigned* __restrict__ scal) {
  const float s = __uint_as_float(scal[2]) / 127.0f + 1e-8f;
  const int g = blockIdx.y, t0 = blockIdx.x * 64;
  const int b = g >> 4, h = g & 15;
  __shared__ signed char tile[64][68];
  const int tid = threadIdx.x;
#pragma unroll
  for (int rep = 0; rep < 4; ++rep) {
    int tl = tid >> 2;
    int f4 = (tid & 3) + rep * 4;
    const float* p = qkv32 + ((size_t)(t0 + tl) * B_DIM + b) * 3072 + 2048 + h * 64 + f4 * 4;
    float4 x = *reinterpret_cast<const float4*>(p);
    char4 c;
    { float q = rintf(x.x / s); q = fminf(127.f, fmaxf(-127.f, q)); c.x = (signed char)q; }
    { float q = rintf(x.y / s); q = fminf(127.f, fmaxf(-127.f, q)); c.y = (signed char)q; }
    { float q = rintf(x.z / s); q = fminf(127.f, fmaxf(-127.f, q)); c.z = (signed char)q; }
    { float q = rintf(x.w / s); q = fminf(127.f, fmaxf(-127.f, q)); c.w = (signed char)q; }
    *reinterpret_cast<char4*>(&tile[tl][f4 * 4]) = c;
  }
  __syncthreads();
  const int dh = tid >> 2, tq = tid & 3;
  signed char outb[16];
#pragma unroll
  for (int j = 0; j < 16; ++j) outb[j] = tile[tq * 16 + j][dh];
  i32x4 vv;
  __builtin_memcpy(&vv, outb, 16);
  *reinterpret_cast<i32x4*>(viT8 + ((size_t)g * DH + dh) * T_DIM + t0 + tq * 16) = vv;
}

// ---------- in-register 4x4 dword transpose across lanes {lo, lo+16, lo+32, lo+48} ----------
static __device__ __forceinline__ void xpose4(int h, int& p0, int& p1, int& p2, int& p3) {
  const bool b0 = (h & 1), b1 = (h & 2);
  int s0 = __shfl_xor(p0, 16), s1 = __shfl_xor(p1, 16);
  int s2 = __shfl_xor(p2, 16), s3 = __shfl_xor(p3, 16);
  int q0 = b0 ? s1 : p0;
  int q1 = b0 ? p1 : s0;
  int q2 = b0 ? s3 : p2;
  int q3 = b0 ? p3 : s2;
  int u0 = __shfl_xor(q0, 32), u1 = __shfl_xor(q1, 32);
  int u2 = __shfl_xor(q2, 32), u3 = __shfl_xor(q3, 32);
  p0 = b1 ? u2 : q0;
  p1 = b1 ? u3 : q1;
  p2 = b1 ? q2 : u0;
  p3 = b1 ? q3 : u1;
}

// ---------- pass1: global max|idot|; 512 thr, waves 0-3 / 4-7 split k ----------
__global__ __launch_bounds__(512, 8) void attn_smax_kernel(const signed char* __restrict__ qi8,
                                                           const signed char* __restrict__ ki8,
                                                           unsigned* __restrict__ scal) {
  const int tid = threadIdx.x;
  const int lane = tid & 63, wave = tid >> 6;
  const int g = blockIdx.y;
  const int qb = blockIdx.x * 64 + (wave & 3) * 16;
  const int k0 = (wave >> 2) * (T_DIM / 2);
  const int lo = lane & 15, hi4 = lane >> 4;
  const signed char* qg = qi8 + (size_t)g * T_DIM * DH;
  const signed char* kg = ki8 + (size_t)g * T_DIM * DH;
  const i32x4 qfr = *reinterpret_cast<const i32x4*>(qg + (size_t)(qb + lo) * DH + hi4 * 16);
  const i32x4 zero = {0, 0, 0, 0};
  int mx = -2147483647, mn = 2147483647;
#pragma unroll 4
  for (int kc = k0; kc < k0 + T_DIM / 2; kc += 16) {
    i32x4 kfr = *reinterpret_cast<const i32x4*>(kg + (size_t)(kc + lo) * DH + hi4 * 16);
    i32x4 sc = __builtin_amdgcn_mfma_i32_16x16x64_i8(kfr, qfr, zero, 0, 0, 0);
#pragma unroll
    for (int r = 0; r < 4; ++r) { mx = sc[r] > mx ? sc[r] : mx; mn = sc[r] < mn ? sc[r] : mn; }
  }
  int am = mx > -mn ? mx : -mn;
#pragma unroll
  for (int s = 32; s; s >>= 1) { int o = __shfl_xor(am, s); am = o > am ? o : am; }
  __shared__ int sm;
  if (tid == 0) sm = 0;
  __syncthreads();
  if (lane == 0) atomicMax(&sm, am);
  __syncthreads();
  if (tid == 0) atomicMax((int*)&scal[3], sm);
}

// ---------- pass2: per-row lmax & Z via dword exp-LUT; 512 thr, k-split ----------
__global__ __launch_bounds__(512, 8) void attn_stats_kernel(const signed char* __restrict__ qi8,
                                                            const signed char* __restrict__ ki8,
                                                            unsigned* __restrict__ scal,
                                                            float* __restrict__ rowZ,
                                                            float* __restrict__ rowL) {
  const float sq = __uint_as_float(scal[0]) / 127.0f + 1e-8f;
  const float sk = __uint_as_float(scal[1]) / 127.0f + 1e-8f;
  const float sqsk = sq * sk;
  const float smax = sqsk * (float)(int)scal[3];
  const float s_s = smax / 127.0f + 1e-8f;
  const float ratio = sqsk / s_s;
  const float a = s_s * 1.4426950408889634f;   // s_s * log2(e)
  const float c = -127.0f * a;
  __shared__ float gLut[256];
  __shared__ int cmx[4][16];
  __shared__ float czp[4][16];
  __shared__ unsigned szm;
  const int tid = threadIdx.x;
  if (tid < 255) gLut[tid] = exp2f(fmaf((float)(tid - 127), a, c));  // same fp ops as before
  if (tid == 0) szm = 0x7F800000u;
  __syncthreads();
  const int lane = tid & 63, wave = tid >> 6;
  const int g = blockIdx.y;
  const int qb = blockIdx.x * 64 + (wave & 3) * 16;
  const int k0 = (wave >> 2) * (T_DIM / 2);
  const int lo = lane & 15, hi4 = lane >> 4;
  const signed char* qg = qi8 + (size_t)g * T_DIM * DH;
  const signed char* kg = ki8 + (size_t)g * T_DIM * DH;
  const i32x4 qfr = *reinterpret_cast<const i32x4*>(qg + (size_t)(qb + lo) * DH + hi4 * 16);
  const i32x4 zero = {0, 0, 0, 0};
  int scmax = -2147483647;
  float zp = 0.f;
#pragma unroll 4
  for (int kc = k0; kc < k0 + T_DIM / 2; kc += 16) {
    i32x4 kfr = *reinterpret_cast<const i32x4*>(kg + (size_t)(kc + lo) * DH + hi4 * 16);
    i32x4 sc = __builtin_amdgcn_mfma_i32_16x16x64_i8(kfr, qfr, zero, 0, 0, 0);
#pragma unroll
    for (int r = 0; r < 4; ++r) {
      scmax = sc[r] > scmax ? sc[r] : scmax;
      int idx = (int)rintf((float)sc[r] * ratio) + 127;
      zp += gLut[idx];
    }
  }
  // intra-wave reduce over the 4 hi4 groups (row = qb+lo)
  { int o = __shfl_xor(scmax, 16); scmax = o > scmax ? o : scmax; }
  zp += __shfl_xor(zp, 16);
  { int o = __shfl_xor(scmax, 32); scmax = o > scmax ? o : scmax; }
  zp += __shfl_xor(zp, 32);
  // cross k-half combine: upper waves publish, lower waves merge
  if (wave >= 4 && hi4 == 0) { cmx[wave - 4][lo] = scmax; czp[wave - 4][lo] = zp; }
  __syncthreads();
  if (wave < 4) {
    int o = cmx[wave][lo];
    scmax = o > scmax ? o : scmax;
    zp += czp[wave][lo];
    float mx = rintf((float)scmax * ratio);    // rint monotone: max(rint)=rint(max)
    float Z = zp * exp2f((127.0f - mx) * a);   // true softmax denom, <= 2048
    if (hi4 == 0) {
      rowZ[(size_t)g * T_DIM + qb + lo] = Z;
      rowL[(size_t)g * T_DIM + qb + lo] = mx;
    }
    float zm = Z;
#pragma unroll
    for (int s = 32; s; s >>= 1) zm = fminf(zm, __shfl_xor(zm, s));
    if (lane == 0) atomicMin(&szm, __float_as_uint(zm));
  }
  __syncthreads();
  if (tid == 0) atomicMin(&scal[4], szm);
}

// ---------- pass3: swapped QK -> arithmetic P-quant (+2^23 RNE) -> xpose -> PV ----------
// 512 thr: waves 0-3 k-half 0, waves 4-7 k-half 1; i32 acc combined via LDS.
__global__ __launch_bounds__(512, 8) void attn_pv_kernel(const signed char* __restrict__ qi8,
                                                         const signed char* __restrict__ ki8,
                                                         const signed char* __restrict__ viT8,
                                                         const float* __restrict__ rowZ,
                                                         const float* __restrict__ rowL,
                                                         unsigned* __restrict__ scal,
                                                         int* __restrict__ attn_out) {
  const float sq = __uint_as_float(scal[0]) / 127.0f + 1e-8f;
  const float sk = __uint_as_float(scal[1]) / 127.0f + 1e-8f;
  const float sqsk = sq * sk;
  const float smax = sqsk * (float)(int)scal[3];
  const float s_s = smax / 127.0f + 1e-8f;
  const float ratio = sqsk / s_s;
  const float a = s_s * 1.4426950408889634f;
  const float maxp = 1.0f / __uint_as_float(scal[4]);
  const float s_p = maxp / 127.0f + 1e-8f;
  const int tid = threadIdx.x;
  const int lane = tid & 63, wave = tid >> 6;
  const int g = blockIdx.y;
  const int qb = blockIdx.x * 64 + (wave & 3) * 16;
  const int k0 = (wave >> 2) * (T_DIM / 2);
  const int lo = lane & 15, hi4 = lane >> 4;

  const signed char* qg = qi8 + (size_t)g * T_DIM * DH;
  const signed char* kg = ki8 + (size_t)g * T_DIM * DH;
  const signed char* vg = viT8 + (size_t)g * DH * T_DIM;
  const i32x4 qfr = *reinterpret_cast<const i32x4*>(qg + (size_t)(qb + lo) * DH + hi4 * 16);
  // bexp = -lmax*a - log2(Z*s_p): p_int = rne(exp2(lf*a + bexp)), bounded by 127.0001
  const float Zr = rowZ[(size_t)g * T_DIM + qb + lo];
  const float lm = rowL[(size_t)g * T_DIM + qb + lo];
  const float bexp = fmaf(-lm, a, -__log2f(Zr * s_p));
  const i32x4 zero = {0, 0, 0, 0};
  i32x4 accv[4];
#pragma unroll
  for (int dt = 0; dt < 4; ++dt) accv[dt] = zero;

  for (int kc = k0; kc < k0 + T_DIM / 2; kc += 64) {
    int pk[4];
#pragma unroll
    for (int t = 0; t < 4; ++t) {
      i32x4 kfr =
          *reinterpret_cast<const i32x4*>(kg + (size_t)(kc + t * 16 + lo) * DH + hi4 * 16);
      i32x4 sc = __builtin_amdgcn_mfma_i32_16x16x64_i8(kfr, qfr, zero, 0, 0, 0);
      unsigned u0, u1, u2, u3;
      { float lf = rintf((float)sc[0] * ratio);
        u0 = __float_as_uint(exp2f(fmaf(lf, a, bexp)) + 8388608.0f); }
      { float lf = rintf((float)sc[1] * ratio);
        u1 = __float_as_uint(exp2f(fmaf(lf, a, bexp)) + 8388608.0f); }
      { float lf = rintf((float)sc[2] * ratio);
        u2 = __float_as_uint(exp2f(fmaf(lf, a, bexp)) + 8388608.0f); }
      { float lf = rintf((float)sc[3] * ratio);
        u3 = __float_as_uint(exp2f(fmaf(lf, a, bexp)) + 8388608.0f); }
      pk[t] = (int)((u0 & 255u) | ((u1 & 255u) << 8) | ((u2 & 255u) << 16) | (u3 << 24));
    }
    xpose4(hi4, pk[0], pk[1], pk[2], pk[3]);
    const i32x4 pfr = {pk[0], pk[1], pk[2], pk[3]};
#pragma unroll
    for (int dt = 0; dt < 4; ++dt) {
      i32x4 vfr =
          *reinterpret_cast<const i32x4*>(vg + (size_t)(dt * 16 + lo) * T_DIM + kc + hi4 * 16);
      accv[dt] = __builtin_amdgcn_mfma_i32_16x16x64_i8(pfr, vfr, accv[dt], 0, 0, 0);
    }
  }
  // combine k-halves through LDS (upper waves publish, lower add + store)
  __shared__ __align__(16) i32x4 cmb[4][64][4];
  __shared__ int sm;
  if (tid == 0) sm = 0;
  if (wave >= 4) {
#pragma unroll
    for (int dt = 0; dt < 4; ++dt) cmb[wave - 4][lane][dt] = accv[dt];
  }
  __syncthreads();
  int am = 0;
  if (wave < 4) {
#pragma unroll
    for (int dt = 0; dt < 4; ++dt) {
      i32x4 o = cmb[wave][lane][dt];
#pragma unroll
      for (int r = 0; r < 4; ++r) {
        int v = accv[dt][r] + o[r];
        attn_out[((size_t)g * T_DIM + qb + hi4 * 4 + r) * DH + dt * 16 + lo] = v;
        int av = v < 0 ? -v : v;
        am = av > am ? av : am;
      }
    }
  }
#pragma unroll
  for (int s = 32; s; s >>= 1) { int o = __shfl_xor(am, s); am = o > am ? o : am; }
  if (lane == 0) atomicMax(&sm, am);
  __syncthreads();
  if (tid == 0) atomicMax((int*)&scal[5], sm);
}

// ---------- pass4: fake-quant attn, reorder [g][t][dh] -> (t,b,d), split to bf16 hi/lo ----------
__global__ __launch_bounds__(256) void quant_attn_kernel(const int* __restrict__ attn_i32,
                                                         unsigned short* __restrict__ aq_hi,
                                                         unsigned short* __restrict__ aq_lo,
                                                         const unsigned* __restrict__ scal) {
  const float sv = __uint_as_float(scal[2]) / 127.0f + 1e-8f;
  const float maxp = 1.0f / __uint_as_float(scal[4]);
  const float s_p = maxp / 127.0f + 1e-8f;
  const float spsv = s_p * sv;
  const float amax = spsv * (float)(int)scal[5];
  const float s_a = amax / 127.0f + 1e-8f;
  size_t i4 = ((size_t)blockIdx.x * 256 + threadIdx.x) * 4;
  i32x4 iv = *reinterpret_cast<const i32x4*>(attn_i32 + i4);
  int dh0 = (int)(i4 & 63);
  int t = (int)((i4 >> 6) & (T_DIM - 1));
  int g = (int)(i4 >> 17);
  int b = g >> 4, h = g & 15;
  ushort4 hh, ll;
  { float v = (float)iv[0] * spsv; float lf = fminf(127.f, fmaxf(-127.f, rintf(v / s_a)));
    float qv = lf * s_a; hh.x = f32_to_bf16_rne(qv); ll.x = f32_to_bf16_rne(qv - bf16_to_f32(hh.x)); }
  { float v = (float)iv[1] * spsv; float lf = fminf(127.f, fmaxf(-127.f, rintf(v / s_a)));
    float qv = lf * s_a; hh.y = f32_to_bf16_rne(qv); ll.y = f32_to_bf16_rne(qv - bf16_to_f32(hh.y)); }
  { float v = (float)iv[2] * spsv; float lf = fminf(127.f, fmaxf(-127.f, rintf(v / s_a)));
    float qv = lf * s_a; hh.z = f32_to_bf16_rne(qv); ll.z = f32_to_bf16_rne(qv - bf16_to_f32(hh.z)); }
  { float v = (float)iv[3] * spsv; float lf = fminf(127.f, fmaxf(-127.f, rintf(v / s_a)));
    float qv = lf * s_a; hh.w = f32_to_bf16_rne(qv); ll.w = f32_to_bf16_rne(qv - bf16_to_f32(hh.w)); }
  size_t o = (size_t)(t * B_DIM + b) * D_DIM + h * 64 + dh0;
  *reinterpret_cast<ushort4*>(aq_hi + o) = hh;
  *reinterpret_cast<ushort4*>(aq_lo + o) = ll;
}

// ---------------- launch ----------------
extern "C" void kernel_launch(void* const* d_in, const int* in_sizes, int n_in,
                              void* d_out, int out_size, void* d_ws, size_t ws_size,
                              hipStream_t stream) {
  (void)in_sizes; (void)n_in; (void)out_size;
  const float* x  = (const float*)d_in[0];
  const float* wq = (const float*)d_in[1];
  const float* bq = (const float*)d_in[2];
  const float* wk = (const float*)d_in[3];
  const float* bk = (const float*)d_in[4];
  const float* wv = (const float*)d_in[5];
  const float* bv = (const float*)d_in[6];
  const float* wo = (const float*)d_in[7];
  const float* bo = (const float*)d_in[8];
  float* out = (float*)d_out;
  char* ws = (char*)d_ws;

  constexpr size_t SZ_ROW   = (size_t)G_DIM * T_DIM * 4;        // 256 KiB
  constexpr size_t SZ_XSPL  = (size_t)N_ROWS * D_DIM * 2;       // 8 MiB
  constexpr size_t SZ_WSPL  = (size_t)4 * D_DIM * D_DIM * 2;    // 8 MiB
  constexpr size_t SZ_QKV   = (size_t)N_ROWS * 3072 * 4;        // 48 MiB
  constexpr size_t SZ_I8    = (size_t)G_DIM * T_DIM * DH;       // 4 MiB
  constexpr size_t OFF_ROWZ = 256;
  constexpr size_t OFF_ROWL = OFF_ROWZ + SZ_ROW;
  constexpr size_t OFF_XHI  = OFF_ROWL + SZ_ROW;
  constexpr size_t OFF_XLO  = OFF_XHI + SZ_XSPL;
  constexpr size_t OFF_WHI  = OFF_XLO + SZ_XSPL;
  constexpr size_t OFF_WLO  = OFF_WHI + SZ_WSPL;
  constexpr size_t OFF_QKV  = OFF_WLO + SZ_WSPL;
  constexpr size_t OFF_QI8  = OFF_QKV + SZ_QKV;
  constexpr size_t OFF_KI8  = OFF_QI8 + SZ_I8;
  constexpr size_t OFF_VIT8 = OFF_KI8 + SZ_I8;
  constexpr size_t OFF_END  = OFF_VIT8 + SZ_I8;  // ~92.5 MiB
  if (ws_size < OFF_END) return;

  unsigned* scal = (unsigned*)ws;  // [0]amax_q [1]amax_k [2]amax_v [3]score_absint [4]minZ [5]attn_absint [6]amax_out(dummy)
  float* rowZ = (float*)(ws + OFF_ROWZ);
  float* rowL = (float*)(ws + OFF_ROWL);
  unsigned short* x_hi = (unsigned short*)(ws + OFF_XHI);
  unsigned short* x_lo = (unsigned short*)(ws + OFF_XLO);
  unsigned short* w_hi = (unsigned short*)(ws + OFF_WHI);
  unsigned short* w_lo = (unsigned short*)(ws + OFF_WLO);
  float* qkv32 = (float*)(ws + OFF_QKV);
  signed char* qi8 = (signed char*)(ws + OFF_QI8);
  signed char* ki8 = (signed char*)(ws + OFF_KI8);
  signed char* viT8 = (signed char*)(ws + OFF_VIT8);
  int* attn_i32 = (int*)(ws + OFF_QKV);             // alias: qkv32 dead after quant passes
  unsigned short* aq_hi = x_hi;                     // alias: x splits dead after qkv GEMM
  unsigned short* aq_lo = x_lo;

  hipMemsetAsync(ws, 0, 64, stream);
  split_x_kernel<<<4096, 256, 0, stream>>>(x, x_hi, x_lo);
  split_w_kernel<<<dim3(1024, 1, 4), 256, 0, stream>>>(wq, wk, wv, wo, w_hi, w_lo);
  gemm_bf16x3_v3<<<768, 256, 0, stream>>>(x_hi, x_lo, w_hi, w_lo, bq, bk, bv, qkv32, 3072,
                                          scal, 0.125f);
  quant_qk_kernel<<<dim3(4096, 2), 256, 0, stream>>>(qkv32, qi8, ki8, scal);
  quant_v_kernel<<<dim3(32, 32), 256, 0, stream>>>(qkv32, viT8, scal);
  attn_smax_kernel<<<dim3(32, 32), 512, 0, stream>>>(qi8, ki8, scal);
  attn_stats_kernel<<<dim3(32, 32), 512, 0, stream>>>(qi8, ki8, scal, rowZ, rowL);
  attn_pv_kernel<<<dim3(32, 32), 512, 0, stream>>>(qi8, ki8, viT8, rowZ, rowL, scal, attn_i32);
  quant_attn_kernel<<<4096, 256, 0, stream>>>(attn_i32, aq_hi, aq_lo, scal);
  gemm_bf16x3_v3<<<256, 256, 0, stream>>>(aq_hi, aq_lo, w_hi + 3145728, w_lo + 3145728, bo, bo,
                                          bo, out, 1024, scal + 6, 1.0f);
}